// Round 1
// baseline (2647.431 us; speedup 1.0000x reference)
//
#include <hip/hip_runtime.h>
#include <hip/hip_bf16.h>

namespace {

constexpr int B_ = 2, H_ = 48, W_ = 48, DM_ = 96, DI_ = 192, NS_ = 16, RK_ = 6, K_ = 6;
constexpr int L_ = H_ * W_;

__device__ __forceinline__ float sigmoidf_(float x) { return 1.f / (1.f + expf(-x)); }

// ---------------------------------------------------------------------------
// K1: in_proj for x,y (first DI rows) and z-gate (rows DI..2DI) + SiLU(z)
// grid = B*L blocks, 192 threads (one per output channel d)
// ---------------------------------------------------------------------------
__global__ void k_inproj(const float* __restrict__ x, const float* __restrict__ y,
                         const float* __restrict__ kin, const float* __restrict__ Wp,
                         float* __restrict__ xv, float* __restrict__ yv,
                         float* __restrict__ zg) {
  int bl = blockIdx.x;
  int d = threadIdx.x;
  __shared__ float sx[DM_], sy[DM_], sk[DM_];
  if (d < DM_) {
    sx[d] = x[(size_t)bl * DM_ + d];
    sy[d] = y[(size_t)bl * DM_ + d];
    sk[d] = kin[(size_t)bl * DM_ + d];
  }
  __syncthreads();
  const float* w1 = Wp + (size_t)d * DM_;         // row d         (xv/yv)
  const float* w2 = Wp + (size_t)(DI_ + d) * DM_; // row DI+d      (z)
  float ax = 0.f, ay = 0.f, az = 0.f;
#pragma unroll 8
  for (int c = 0; c < DM_; ++c) {
    float w = w1[c];
    ax += sx[c] * w;
    ay += sy[c] * w;
    az += sk[c] * w2[c];
  }
  xv[(size_t)bl * DI_ + d] = ax;
  yv[(size_t)bl * DI_ + d] = ay;
  zg[(size_t)bl * DI_ + d] = az * sigmoidf_(az);
}

// ---------------------------------------------------------------------------
// K2: depthwise 3x3 conv (pad 1) + bias + SiLU.  in/out layout (B, L, DI)
// grid = B*L, 192 threads
// ---------------------------------------------------------------------------
__global__ void k_conv(const float* __restrict__ in, const float* __restrict__ cw,
                       const float* __restrict__ cb, float* __restrict__ out) {
  int bl = blockIdx.x;
  int d = threadIdx.x;
  int b = bl / L_, l = bl % L_;
  int h = l / W_, w = l % W_;
  float acc = cb[d];
  const float* wp = cw + d * 9;
#pragma unroll
  for (int kh = 0; kh < 3; ++kh) {
    int hh = h + kh - 1;
    if (hh < 0 || hh >= H_) continue;
#pragma unroll
    for (int kw = 0; kw < 3; ++kw) {
      int ww = w + kw - 1;
      if (ww < 0 || ww >= W_) continue;
      acc += in[((size_t)b * L_ + hh * W_ + ww) * DI_ + d] * wp[kh * 3 + kw];
    }
  }
  out[(size_t)bl * DI_ + d] = acc * sigmoidf_(acc);
}

// ---------------------------------------------------------------------------
// K3: build the 6 direction streams xs in (B, K, L, D) layout.
//  k=0: row-major xc;  k=1: column-major yc;  k=2: diagonal-gathered yc;
//  k=3..5: l-flipped copies of k-3.
// grid = B*L, 192 threads
// ---------------------------------------------------------------------------
__global__ void k_build_xs(const float* __restrict__ xc, const float* __restrict__ yc,
                           float* __restrict__ xs) {
  int bl = blockIdx.x;
  int d = threadIdx.x;
  int b = bl / L_, l = bl % L_;
  int h = l / W_, w = l % W_;
  float vx = xc[(size_t)bl * DI_ + d];
  float vy = yc[(size_t)bl * DI_ + d];
  float vd = yc[((size_t)b * L_ + h * W_ + (h + w) % W_) * DI_ + d];
  size_t base = (size_t)b * K_ * L_;
  int lv = w * H_ + h;
  xs[(base + (size_t)0 * L_ + l) * DI_ + d] = vx;
  xs[(base + (size_t)1 * L_ + lv) * DI_ + d] = vy;
  xs[(base + (size_t)2 * L_ + lv) * DI_ + d] = vd;
  xs[(base + (size_t)3 * L_ + (L_ - 1 - l)) * DI_ + d] = vx;
  xs[(base + (size_t)4 * L_ + (L_ - 1 - lv)) * DI_ + d] = vy;
  xs[(base + (size_t)5 * L_ + (L_ - 1 - lv)) * DI_ + d] = vd;
}

// ---------------------------------------------------------------------------
// K4: x_dbl = x_proj_w @ xs_row (38 outputs), then delta = softplus(dt_w@r + dt_b),
//     Bs = x_dbl[6:22], Cs = x_dbl[22:38].
// grid = B*K*L (idx = (b*K + k)*L + l), 192 threads
// ---------------------------------------------------------------------------
__global__ void k_xdbl(const float* __restrict__ xs, const float* __restrict__ xpw,
                       const float* __restrict__ dtw, const float* __restrict__ dtb,
                       float* __restrict__ delta, float* __restrict__ Bsb,
                       float* __restrict__ Csb) {
  int idx = blockIdx.x;
  int d = threadIdx.x;
  int k = (idx / L_) % K_;
  __shared__ float row[DI_];
  __shared__ float xdbl[RK_ + 2 * NS_];
  row[d] = xs[(size_t)idx * DI_ + d];
  __syncthreads();
  if (d < RK_ + 2 * NS_) {
    const float* wp = xpw + ((size_t)k * (RK_ + 2 * NS_) + d) * DI_;
    float a = 0.f;
#pragma unroll 8
    for (int c = 0; c < DI_; ++c) a += row[c] * wp[c];
    xdbl[d] = a;
  }
  __syncthreads();
  const float* dw = dtw + ((size_t)k * DI_ + d) * RK_;
  float s = dtb[k * DI_ + d];
#pragma unroll
  for (int r = 0; r < RK_; ++r) s += xdbl[r] * dw[r];
  float dl = (s > 20.f) ? s : log1pf(expf(s));
  delta[(size_t)idx * DI_ + d] = dl;
  if (d < NS_) {
    Bsb[(size_t)idx * NS_ + d] = xdbl[RK_ + d];
    Csb[(size_t)idx * NS_ + d] = xdbl[RK_ + NS_ + d];
  }
}

// ---------------------------------------------------------------------------
// K5: sequential selective scan. One thread per (b,k,d) lane, 16-state regs.
// grid = B*K blocks (bk), 192 threads. out_y layout (B,K,L,D).
// ---------------------------------------------------------------------------
__global__ void k_scan(const float* __restrict__ delta, const float* __restrict__ xs,
                       const float* __restrict__ Bsb, const float* __restrict__ Csb,
                       const float* __restrict__ A_logs, const float* __restrict__ Ds,
                       float* __restrict__ out_y) {
  int bk = blockIdx.x;           // b*K + k
  int k = bk % K_;
  int d = threadIdx.x;
  float A[NS_];
#pragma unroll
  for (int n = 0; n < NS_; ++n) A[n] = -expf(A_logs[((size_t)k * DI_ + d) * NS_ + n]);
  float Dk = Ds[k * DI_ + d];
  float hst[NS_];
#pragma unroll
  for (int n = 0; n < NS_; ++n) hst[n] = 0.f;
  size_t base = (size_t)bk * L_;
  for (int l = 0; l < L_; ++l) {
    float dl = delta[(base + l) * DI_ + d];
    float u = xs[(base + l) * DI_ + d];
    float du = dl * u;
    const float* Bp = Bsb + (base + l) * NS_;
    const float* Cp = Csb + (base + l) * NS_;
    float yacc = 0.f;
#pragma unroll
    for (int n = 0; n < NS_; ++n) {
      hst[n] = expf(dl * A[n]) * hst[n] + du * Bp[n];
      yacc += hst[n] * Cp[n];
    }
    out_y[(base + l) * DI_ + d] = yacc + Dk * u;
  }
}

// ---------------------------------------------------------------------------
// K6: merge directions (+inverse spatial maps), LayerNorm, gate, out-proj.
// grid = 3*B*L blocks (m = which head), 192 threads.
// ---------------------------------------------------------------------------
__global__ void k_head(const float* __restrict__ out_y, const float* __restrict__ zg,
                       const float* __restrict__ lnw, const float* __restrict__ lnb,
                       const float* __restrict__ opw, float* __restrict__ out) {
  int gb = blockIdx.x;
  int m = gb / (B_ * L_);
  int bl = gb % (B_ * L_);
  int b = bl / L_, lp = bl % L_;
  int h = lp / W_, w = lp % W_;
  int d = threadIdx.x;
  int l0;
  if (m == 0) l0 = lp;
  else if (m == 1) l0 = w * H_ + h;
  else l0 = ((w - h + W_) % W_) * H_ + h;
  size_t basef = ((size_t)b * K_ + m) * L_;        // forward dir m
  size_t baser = ((size_t)b * K_ + m + 3) * L_;    // reversed dir m+3
  float t = out_y[(basef + l0) * DI_ + d] + out_y[(baser + (L_ - 1 - l0)) * DI_ + d];

  __shared__ float tt[DI_];
  __shared__ float red[64];
  tt[d] = t;
  __syncthreads();
  if (d < 64) red[d] = tt[d] + tt[d + 64] + tt[d + 128];
  __syncthreads();
  if (d < 64) {
    float v = red[d];
    for (int off = 32; off; off >>= 1) v += __shfl_down(v, off, 64);
    if (d == 0) red[0] = v;
  }
  __syncthreads();
  float mu = red[0] * (1.f / DI_);
  __syncthreads();
  if (d < 64) {
    float a = tt[d] - mu, b2 = tt[d + 64] - mu, c2 = tt[d + 128] - mu;
    red[d] = a * a + b2 * b2 + c2 * c2;
  }
  __syncthreads();
  if (d < 64) {
    float v = red[d];
    for (int off = 32; off; off >>= 1) v += __shfl_down(v, off, 64);
    if (d == 0) red[0] = v;
  }
  __syncthreads();
  float var = red[0] * (1.f / DI_);
  float g = (t - mu) * rsqrtf(var + 1e-5f) * lnw[d] + lnb[d];
  float val = g * zg[(size_t)bl * DI_ + d];
  __syncthreads();
  tt[d] = val;
  __syncthreads();
  if (d < DM_) {
    const float* wp = opw + (size_t)d * DI_;
    float a = 0.f;
#pragma unroll 8
    for (int c = 0; c < DI_; ++c) a += tt[c] * wp[c];
    out[((size_t)m * (B_ * L_) + bl) * DM_ + d] = a;
  }
}

}  // namespace

extern "C" void kernel_launch(void* const* d_in, const int* in_sizes, int n_in,
                              void* d_out, int out_size, void* d_ws, size_t ws_size,
                              hipStream_t stream) {
  const float* x = (const float*)d_in[0];
  const float* y = (const float*)d_in[1];
  const float* kin = (const float*)d_in[2];
  const float* in_proj_w = (const float*)d_in[3];
  const float* conv_w = (const float*)d_in[4];
  const float* conv_b = (const float*)d_in[5];
  const float* x_proj_w = (const float*)d_in[6];
  const float* dt_w = (const float*)d_in[7];
  const float* dt_b = (const float*)d_in[8];
  const float* A_logs = (const float*)d_in[9];
  const float* Ds = (const float*)d_in[10];
  const float* ln_w = (const float*)d_in[11];
  const float* ln_b = (const float*)d_in[12];
  const float* out_proj_w = (const float*)d_in[13];
  float* out = (float*)d_out;

  float* ws = (float*)d_ws;
  const size_t BLD = (size_t)B_ * L_ * DI_;        // 884736
  const size_t BKLD = (size_t)B_ * K_ * L_ * DI_;  // 5308416
  const size_t BKLN = (size_t)B_ * K_ * L_ * NS_;  // 442368
  float* xv = ws;             ws += BLD;
  float* yv = ws;             ws += BLD;
  float* zg = ws;             ws += BLD;
  float* xc = ws;             ws += BLD;
  float* yc = ws;             ws += BLD;
  float* xs = ws;             ws += BKLD;
  float* delta = ws;          ws += BKLD;
  float* Bsb = ws;            ws += BKLN;
  float* Csb = ws;            ws += BKLN;
  float* out_y = ws;          ws += BKLD;

  dim3 blk(DI_);
  k_inproj<<<B_ * L_, blk, 0, stream>>>(x, y, kin, in_proj_w, xv, yv, zg);
  k_conv<<<B_ * L_, blk, 0, stream>>>(xv, conv_w, conv_b, xc);
  k_conv<<<B_ * L_, blk, 0, stream>>>(yv, conv_w, conv_b, yc);
  k_build_xs<<<B_ * L_, blk, 0, stream>>>(xc, yc, xs);
  k_xdbl<<<B_ * K_ * L_, blk, 0, stream>>>(xs, x_proj_w, dt_w, dt_b, delta, Bsb, Csb);
  k_scan<<<B_ * K_, blk, 0, stream>>>(delta, xs, Bsb, Csb, A_logs, Ds, out_y);
  k_head<<<3 * B_ * L_, blk, 0, stream>>>(out_y, zg, ln_w, ln_b, out_proj_w, out);
}

// Round 2
// 541.536 us; speedup vs baseline: 4.8887x; 4.8887x over previous
//
#include <hip/hip_runtime.h>
#include <hip/hip_bf16.h>

namespace {

constexpr int B_ = 2, H_ = 48, W_ = 48, DM_ = 96, DI_ = 192, NS_ = 16, RK_ = 6, K_ = 6;
constexpr int L_ = H_ * W_;
constexpr int C_ = 48;            // chunks per (b,k) stream
constexpr int LC_ = L_ / C_;      // 48 steps per chunk

__device__ __forceinline__ float sigmoidf_(float x) { return 1.f / (1.f + expf(-x)); }

// ---------------------------------------------------------------------------
// K1: in_proj for x,y (first DI rows) and z-gate (rows DI..2DI) + SiLU(z)
// ---------------------------------------------------------------------------
__global__ void k_inproj(const float* __restrict__ x, const float* __restrict__ y,
                         const float* __restrict__ kin, const float* __restrict__ Wp,
                         float* __restrict__ xv, float* __restrict__ yv,
                         float* __restrict__ zg) {
  int bl = blockIdx.x;
  int d = threadIdx.x;
  __shared__ float sx[DM_], sy[DM_], sk[DM_];
  if (d < DM_) {
    sx[d] = x[(size_t)bl * DM_ + d];
    sy[d] = y[(size_t)bl * DM_ + d];
    sk[d] = kin[(size_t)bl * DM_ + d];
  }
  __syncthreads();
  const float* w1 = Wp + (size_t)d * DM_;
  const float* w2 = Wp + (size_t)(DI_ + d) * DM_;
  float ax = 0.f, ay = 0.f, az = 0.f;
#pragma unroll 8
  for (int c = 0; c < DM_; ++c) {
    float w = w1[c];
    ax += sx[c] * w;
    ay += sy[c] * w;
    az += sk[c] * w2[c];
  }
  xv[(size_t)bl * DI_ + d] = ax;
  yv[(size_t)bl * DI_ + d] = ay;
  zg[(size_t)bl * DI_ + d] = az * sigmoidf_(az);
}

// ---------------------------------------------------------------------------
// K2: depthwise 3x3 conv (pad 1) + bias + SiLU.  layout (B, L, DI)
// ---------------------------------------------------------------------------
__global__ void k_conv(const float* __restrict__ in, const float* __restrict__ cw,
                       const float* __restrict__ cb, float* __restrict__ out) {
  int bl = blockIdx.x;
  int d = threadIdx.x;
  int b = bl / L_, l = bl % L_;
  int h = l / W_, w = l % W_;
  float acc = cb[d];
  const float* wp = cw + d * 9;
#pragma unroll
  for (int kh = 0; kh < 3; ++kh) {
    int hh = h + kh - 1;
    if (hh < 0 || hh >= H_) continue;
#pragma unroll
    for (int kw = 0; kw < 3; ++kw) {
      int ww = w + kw - 1;
      if (ww < 0 || ww >= W_) continue;
      acc += in[((size_t)b * L_ + hh * W_ + ww) * DI_ + d] * wp[kh * 3 + kw];
    }
  }
  out[(size_t)bl * DI_ + d] = acc * sigmoidf_(acc);
}

// ---------------------------------------------------------------------------
// K3: build the 6 direction streams xs in (B, K, L, D) layout.
// ---------------------------------------------------------------------------
__global__ void k_build_xs(const float* __restrict__ xc, const float* __restrict__ yc,
                           float* __restrict__ xs) {
  int bl = blockIdx.x;
  int d = threadIdx.x;
  int b = bl / L_, l = bl % L_;
  int h = l / W_, w = l % W_;
  float vx = xc[(size_t)bl * DI_ + d];
  float vy = yc[(size_t)bl * DI_ + d];
  float vd = yc[((size_t)b * L_ + h * W_ + (h + w) % W_) * DI_ + d];
  size_t base = (size_t)b * K_ * L_;
  int lv = w * H_ + h;
  xs[(base + (size_t)0 * L_ + l) * DI_ + d] = vx;
  xs[(base + (size_t)1 * L_ + lv) * DI_ + d] = vy;
  xs[(base + (size_t)2 * L_ + lv) * DI_ + d] = vd;
  xs[(base + (size_t)3 * L_ + (L_ - 1 - l)) * DI_ + d] = vx;
  xs[(base + (size_t)4 * L_ + (L_ - 1 - lv)) * DI_ + d] = vy;
  xs[(base + (size_t)5 * L_ + (L_ - 1 - lv)) * DI_ + d] = vd;
}

// ---------------------------------------------------------------------------
// K4: x_dbl (38 outputs), delta = softplus(dt_w@r + dt_b), Bs, Cs.
// ---------------------------------------------------------------------------
__global__ void k_xdbl(const float* __restrict__ xs, const float* __restrict__ xpw,
                       const float* __restrict__ dtw, const float* __restrict__ dtb,
                       float* __restrict__ delta, float* __restrict__ Bsb,
                       float* __restrict__ Csb) {
  int idx = blockIdx.x;
  int d = threadIdx.x;
  int k = (idx / L_) % K_;
  __shared__ float row[DI_];
  __shared__ float xdbl[RK_ + 2 * NS_];
  row[d] = xs[(size_t)idx * DI_ + d];
  __syncthreads();
  if (d < RK_ + 2 * NS_) {
    const float* wp = xpw + ((size_t)k * (RK_ + 2 * NS_) + d) * DI_;
    float a = 0.f;
#pragma unroll 8
    for (int c = 0; c < DI_; ++c) a += row[c] * wp[c];
    xdbl[d] = a;
  }
  __syncthreads();
  const float* dw = dtw + ((size_t)k * DI_ + d) * RK_;
  float s = dtb[k * DI_ + d];
#pragma unroll
  for (int r = 0; r < RK_; ++r) s += xdbl[r] * dw[r];
  float dl = (s > 20.f) ? s : log1pf(expf(s));
  delta[(size_t)idx * DI_ + d] = dl;
  if (d < NS_) {
    Bsb[(size_t)idx * NS_ + d] = xdbl[RK_ + d];
    Csb[(size_t)idx * NS_ + d] = xdbl[RK_ + NS_ + d];
  }
}

// ---------------------------------------------------------------------------
// K5a: chunked scan pass 1 — per chunk, transition product P and zero-input
// result S for the 16 states of lane d.  grid = B*K*C_, 192 threads.
// P/S layout: [bk*C_+c][n][d]  (d fastest -> coalesced)
// ---------------------------------------------------------------------------
__global__ void __launch_bounds__(192) k_scan1(
    const float* __restrict__ delta, const float* __restrict__ xs,
    const float* __restrict__ Bsb, const float* __restrict__ A_logs,
    float* __restrict__ Pbuf, float* __restrict__ Sbuf) {
  int blk = blockIdx.x;            // bk*C_ + c
  int bk = blk / C_, c = blk % C_;
  int k = bk % K_;
  int d = threadIdx.x;
  float A[NS_];
#pragma unroll
  for (int n = 0; n < NS_; ++n) A[n] = -expf(A_logs[((size_t)k * DI_ + d) * NS_ + n]);
  float P[NS_], S[NS_];
#pragma unroll
  for (int n = 0; n < NS_; ++n) { P[n] = 1.f; S[n] = 0.f; }
  size_t base = (size_t)bk * L_ + (size_t)c * LC_;
  for (int l = 0; l < LC_; ++l) {
    float dl = delta[(base + l) * DI_ + d];
    float u = xs[(base + l) * DI_ + d];
    float du = dl * u;
    const float* Bp = Bsb + (base + l) * NS_;
#pragma unroll
    for (int n = 0; n < NS_; ++n) {
      float e = expf(dl * A[n]);
      S[n] = e * S[n] + du * Bp[n];
      P[n] *= e;
    }
  }
  size_t ob = (size_t)blk * NS_ * DI_ + d;
#pragma unroll
  for (int n = 0; n < NS_; ++n) {
    Pbuf[ob + (size_t)n * DI_] = P[n];
    Sbuf[ob + (size_t)n * DI_] = S[n];
  }
}

// ---------------------------------------------------------------------------
// K5b: chunk-level scan -> h_in for each chunk.  grid = B*K, 192 threads.
// ---------------------------------------------------------------------------
__global__ void __launch_bounds__(192) k_scan2(
    const float* __restrict__ Pbuf, const float* __restrict__ Sbuf,
    float* __restrict__ Hin) {
  int bk = blockIdx.x;
  int d = threadIdx.x;
  float h[NS_];
#pragma unroll
  for (int n = 0; n < NS_; ++n) h[n] = 0.f;
  for (int c = 0; c < C_; ++c) {
    size_t base = ((size_t)(bk * C_ + c) * NS_) * DI_ + d;
#pragma unroll
    for (int n = 0; n < NS_; ++n) {
      size_t i = base + (size_t)n * DI_;
      Hin[i] = h[n];
      h[n] = Pbuf[i] * h[n] + Sbuf[i];
    }
  }
}

// ---------------------------------------------------------------------------
// K5c: chunked scan pass 3 — recompute recurrence from h_in, emit out_y.
// grid = B*K*C_, 192 threads.
// ---------------------------------------------------------------------------
__global__ void __launch_bounds__(192) k_scan3(
    const float* __restrict__ delta, const float* __restrict__ xs,
    const float* __restrict__ Bsb, const float* __restrict__ Csb,
    const float* __restrict__ A_logs, const float* __restrict__ Ds,
    const float* __restrict__ Hin, float* __restrict__ out_y) {
  int blk = blockIdx.x;            // bk*C_ + c
  int bk = blk / C_, c = blk % C_;
  int k = bk % K_;
  int d = threadIdx.x;
  float A[NS_];
#pragma unroll
  for (int n = 0; n < NS_; ++n) A[n] = -expf(A_logs[((size_t)k * DI_ + d) * NS_ + n]);
  float Dk = Ds[k * DI_ + d];
  float h[NS_];
  size_t hb = (size_t)blk * NS_ * DI_ + d;
#pragma unroll
  for (int n = 0; n < NS_; ++n) h[n] = Hin[hb + (size_t)n * DI_];
  size_t base = (size_t)bk * L_ + (size_t)c * LC_;
  for (int l = 0; l < LC_; ++l) {
    float dl = delta[(base + l) * DI_ + d];
    float u = xs[(base + l) * DI_ + d];
    float du = dl * u;
    const float* Bp = Bsb + (base + l) * NS_;
    const float* Cp = Csb + (base + l) * NS_;
    float yacc = 0.f;
#pragma unroll
    for (int n = 0; n < NS_; ++n) {
      h[n] = expf(dl * A[n]) * h[n] + du * Bp[n];
      yacc += h[n] * Cp[n];
    }
    out_y[(base + l) * DI_ + d] = yacc + Dk * u;
  }
}

// ---------------------------------------------------------------------------
// K6: merge directions, LayerNorm, gate, out-proj.
// ---------------------------------------------------------------------------
__global__ void k_head(const float* __restrict__ out_y, const float* __restrict__ zg,
                       const float* __restrict__ lnw, const float* __restrict__ lnb,
                       const float* __restrict__ opw, float* __restrict__ out) {
  int gb = blockIdx.x;
  int m = gb / (B_ * L_);
  int bl = gb % (B_ * L_);
  int b = bl / L_, lp = bl % L_;
  int h = lp / W_, w = lp % W_;
  int d = threadIdx.x;
  int l0;
  if (m == 0) l0 = lp;
  else if (m == 1) l0 = w * H_ + h;
  else l0 = ((w - h + W_) % W_) * H_ + h;
  size_t basef = ((size_t)b * K_ + m) * L_;
  size_t baser = ((size_t)b * K_ + m + 3) * L_;
  float t = out_y[(basef + l0) * DI_ + d] + out_y[(baser + (L_ - 1 - l0)) * DI_ + d];

  __shared__ float tt[DI_];
  __shared__ float red[64];
  tt[d] = t;
  __syncthreads();
  if (d < 64) red[d] = tt[d] + tt[d + 64] + tt[d + 128];
  __syncthreads();
  if (d < 64) {
    float v = red[d];
    for (int off = 32; off; off >>= 1) v += __shfl_down(v, off, 64);
    if (d == 0) red[0] = v;
  }
  __syncthreads();
  float mu = red[0] * (1.f / DI_);
  __syncthreads();
  if (d < 64) {
    float a = tt[d] - mu, b2 = tt[d + 64] - mu, c2 = tt[d + 128] - mu;
    red[d] = a * a + b2 * b2 + c2 * c2;
  }
  __syncthreads();
  if (d < 64) {
    float v = red[d];
    for (int off = 32; off; off >>= 1) v += __shfl_down(v, off, 64);
    if (d == 0) red[0] = v;
  }
  __syncthreads();
  float var = red[0] * (1.f / DI_);
  float g = (t - mu) * rsqrtf(var + 1e-5f) * lnw[d] + lnb[d];
  float val = g * zg[(size_t)bl * DI_ + d];
  __syncthreads();
  tt[d] = val;
  __syncthreads();
  if (d < DM_) {
    const float* wp = opw + (size_t)d * DI_;
    float a = 0.f;
#pragma unroll 8
    for (int c = 0; c < DI_; ++c) a += tt[c] * wp[c];
    out[((size_t)m * (B_ * L_) + bl) * DM_ + d] = a;
  }
}

}  // namespace

extern "C" void kernel_launch(void* const* d_in, const int* in_sizes, int n_in,
                              void* d_out, int out_size, void* d_ws, size_t ws_size,
                              hipStream_t stream) {
  const float* x = (const float*)d_in[0];
  const float* y = (const float*)d_in[1];
  const float* kin = (const float*)d_in[2];
  const float* in_proj_w = (const float*)d_in[3];
  const float* conv_w = (const float*)d_in[4];
  const float* conv_b = (const float*)d_in[5];
  const float* x_proj_w = (const float*)d_in[6];
  const float* dt_w = (const float*)d_in[7];
  const float* dt_b = (const float*)d_in[8];
  const float* A_logs = (const float*)d_in[9];
  const float* Ds = (const float*)d_in[10];
  const float* ln_w = (const float*)d_in[11];
  const float* ln_b = (const float*)d_in[12];
  const float* out_proj_w = (const float*)d_in[13];
  float* out = (float*)d_out;

  float* ws = (float*)d_ws;
  const size_t BLD = (size_t)B_ * L_ * DI_;                 // 884736
  const size_t BKLD = (size_t)B_ * K_ * L_ * DI_;           // 5308416
  const size_t BKLN = (size_t)B_ * K_ * L_ * NS_;           // 442368
  const size_t PSN = (size_t)B_ * K_ * C_ * NS_ * DI_;      // 1769472
  float* xv = ws;             ws += BLD;
  float* yv = ws;             ws += BLD;
  float* zg = ws;             ws += BLD;
  float* xc = ws;             ws += BLD;
  float* yc = ws;             ws += BLD;
  float* xs = ws;             ws += BKLD;
  float* delta = ws;          ws += BKLD;
  float* Bsb = ws;            ws += BKLN;
  float* Csb = ws;            ws += BKLN;
  float* out_y = ws;          ws += BKLD;
  float* Hin = ws;            ws += PSN;
  // P/S alias buffers that are dead once k_build_xs has run:
  float* Pbuf = xv;   // spans xv+yv  (2*BLD == PSN)
  float* Sbuf = xc;   // spans xc+yc  (2*BLD == PSN)

  dim3 blk(DI_);
  k_inproj<<<B_ * L_, blk, 0, stream>>>(x, y, kin, in_proj_w, xv, yv, zg);
  k_conv<<<B_ * L_, blk, 0, stream>>>(xv, conv_w, conv_b, xc);
  k_conv<<<B_ * L_, blk, 0, stream>>>(yv, conv_w, conv_b, yc);
  k_build_xs<<<B_ * L_, blk, 0, stream>>>(xc, yc, xs);
  k_xdbl<<<B_ * K_ * L_, blk, 0, stream>>>(xs, x_proj_w, dt_w, dt_b, delta, Bsb, Csb);
  k_scan1<<<B_ * K_ * C_, blk, 0, stream>>>(delta, xs, Bsb, A_logs, Pbuf, Sbuf);
  k_scan2<<<B_ * K_, blk, 0, stream>>>(Pbuf, Sbuf, Hin);
  k_scan3<<<B_ * K_ * C_, blk, 0, stream>>>(delta, xs, Bsb, Csb, A_logs, Ds, Hin, out_y);
  k_head<<<3 * B_ * L_, blk, 0, stream>>>(out_y, zg, ln_w, ln_b, out_proj_w, out);
}

// Round 3
// 434.440 us; speedup vs baseline: 6.0939x; 1.2465x over previous
//
#include <hip/hip_runtime.h>
#include <hip/hip_bf16.h>

namespace {

constexpr int B_ = 2, H_ = 48, W_ = 48, DM_ = 96, DI_ = 192, NS_ = 16, RK_ = 6, K_ = 6;
constexpr int L_ = H_ * W_;
constexpr int C_ = 48;            // chunks per (b,k) stream
constexpr int LC_ = L_ / C_;      // 48 steps per chunk
constexpr int NPROJ = RK_ + 2 * NS_;  // 38

__device__ __forceinline__ float sigmoidf_(float x) { return 1.f / (1.f + expf(-x)); }

// ---------------------------------------------------------------------------
// K1: in_proj for x,y (first DI rows) and z-gate (rows DI..2DI) + SiLU(z)
// ---------------------------------------------------------------------------
__global__ void k_inproj(const float* __restrict__ x, const float* __restrict__ y,
                         const float* __restrict__ kin, const float* __restrict__ Wp,
                         float* __restrict__ xv, float* __restrict__ yv,
                         float* __restrict__ zg) {
  int bl = blockIdx.x;
  int d = threadIdx.x;
  __shared__ float sx[DM_], sy[DM_], sk[DM_];
  if (d < DM_) {
    sx[d] = x[(size_t)bl * DM_ + d];
    sy[d] = y[(size_t)bl * DM_ + d];
    sk[d] = kin[(size_t)bl * DM_ + d];
  }
  __syncthreads();
  const float* w1 = Wp + (size_t)d * DM_;
  const float* w2 = Wp + (size_t)(DI_ + d) * DM_;
  float ax = 0.f, ay = 0.f, az = 0.f;
#pragma unroll 8
  for (int c = 0; c < DM_; ++c) {
    float w = w1[c];
    ax += sx[c] * w;
    ay += sy[c] * w;
    az += sk[c] * w2[c];
  }
  xv[(size_t)bl * DI_ + d] = ax;
  yv[(size_t)bl * DI_ + d] = ay;
  zg[(size_t)bl * DI_ + d] = az * sigmoidf_(az);
}

// ---------------------------------------------------------------------------
// K2: depthwise 3x3 conv (pad 1) + bias + SiLU.  layout (B, L, DI)
// ---------------------------------------------------------------------------
__global__ void k_conv(const float* __restrict__ in, const float* __restrict__ cw,
                       const float* __restrict__ cb, float* __restrict__ out) {
  int bl = blockIdx.x;
  int d = threadIdx.x;
  int b = bl / L_, l = bl % L_;
  int h = l / W_, w = l % W_;
  float acc = cb[d];
  const float* wp = cw + d * 9;
#pragma unroll
  for (int kh = 0; kh < 3; ++kh) {
    int hh = h + kh - 1;
    if (hh < 0 || hh >= H_) continue;
#pragma unroll
    for (int kw = 0; kw < 3; ++kw) {
      int ww = w + kw - 1;
      if (ww < 0 || ww >= W_) continue;
      acc += in[((size_t)b * L_ + hh * W_ + ww) * DI_ + d] * wp[kh * 3 + kw];
    }
  }
  out[(size_t)bl * DI_ + d] = acc * sigmoidf_(acc);
}

// ---------------------------------------------------------------------------
// K3: build the 6 direction streams xs in (B, K, L, D) layout.
// ---------------------------------------------------------------------------
__global__ void k_build_xs(const float* __restrict__ xc, const float* __restrict__ yc,
                           float* __restrict__ xs) {
  int bl = blockIdx.x;
  int d = threadIdx.x;
  int b = bl / L_, l = bl % L_;
  int h = l / W_, w = l % W_;
  float vx = xc[(size_t)bl * DI_ + d];
  float vy = yc[(size_t)bl * DI_ + d];
  float vd = yc[((size_t)b * L_ + h * W_ + (h + w) % W_) * DI_ + d];
  size_t base = (size_t)b * K_ * L_;
  int lv = w * H_ + h;
  xs[(base + (size_t)0 * L_ + l) * DI_ + d] = vx;
  xs[(base + (size_t)1 * L_ + lv) * DI_ + d] = vy;
  xs[(base + (size_t)2 * L_ + lv) * DI_ + d] = vd;
  xs[(base + (size_t)3 * L_ + (L_ - 1 - l)) * DI_ + d] = vx;
  xs[(base + (size_t)4 * L_ + (L_ - 1 - lv)) * DI_ + d] = vy;
  xs[(base + (size_t)5 * L_ + (L_ - 1 - lv)) * DI_ + d] = vd;
}

// ---------------------------------------------------------------------------
// K4: x_dbl (38 outputs via 4-lane groups), delta = softplus, Bs, Cs.
// ---------------------------------------------------------------------------
__global__ void k_xdbl(const float* __restrict__ xs, const float* __restrict__ xpw,
                       const float* __restrict__ dtw, const float* __restrict__ dtb,
                       float* __restrict__ delta, float* __restrict__ Bsb,
                       float* __restrict__ Csb) {
  int idx = blockIdx.x;
  int d = threadIdx.x;
  int k = (idx / L_) % K_;
  __shared__ float row[DI_];
  __shared__ float xdbl[NPROJ];
  row[d] = xs[(size_t)idx * DI_ + d];
  __syncthreads();
  int g = d >> 2, q = d & 3;
  if (g < NPROJ) {
    const float* wp = xpw + ((size_t)k * NPROJ + g) * DI_;
    float a = 0.f;
#pragma unroll 12
    for (int c = q; c < DI_; c += 4) a += row[c] * wp[c];
    a += __shfl_xor(a, 1, 64);
    a += __shfl_xor(a, 2, 64);
    if (q == 0) xdbl[g] = a;
  }
  __syncthreads();
  const float* dw = dtw + ((size_t)k * DI_ + d) * RK_;
  float s = dtb[k * DI_ + d];
#pragma unroll
  for (int r = 0; r < RK_; ++r) s += xdbl[r] * dw[r];
  float dl = (s > 20.f) ? s : log1pf(expf(s));
  delta[(size_t)idx * DI_ + d] = dl;
  if (d < NS_) {
    Bsb[(size_t)idx * NS_ + d] = xdbl[RK_ + d];
    Csb[(size_t)idx * NS_ + d] = xdbl[RK_ + NS_ + d];
  }
}

// ---------------------------------------------------------------------------
// K5a: chunked scan pass 1 — per-chunk transition product P, zero-input S.
// ---------------------------------------------------------------------------
__global__ void __launch_bounds__(192) k_scan1(
    const float* __restrict__ delta, const float* __restrict__ xs,
    const float* __restrict__ Bsb, const float* __restrict__ A_logs,
    float* __restrict__ Pbuf, float* __restrict__ Sbuf) {
  int blk = blockIdx.x;            // bk*C_ + c
  int bk = blk / C_, c = blk % C_;
  int k = bk % K_;
  int d = threadIdx.x;
  float A[NS_];
#pragma unroll
  for (int n = 0; n < NS_; ++n) A[n] = -expf(A_logs[((size_t)k * DI_ + d) * NS_ + n]);
  float P[NS_], S[NS_];
#pragma unroll
  for (int n = 0; n < NS_; ++n) { P[n] = 1.f; S[n] = 0.f; }
  size_t base = (size_t)bk * L_ + (size_t)c * LC_;
  for (int l = 0; l < LC_; ++l) {
    float dl = delta[(base + l) * DI_ + d];
    float u = xs[(base + l) * DI_ + d];
    float du = dl * u;
    const float* Bp = Bsb + (base + l) * NS_;
#pragma unroll
    for (int n = 0; n < NS_; ++n) {
      float e = expf(dl * A[n]);
      S[n] = e * S[n] + du * Bp[n];
      P[n] *= e;
    }
  }
  size_t ob = (size_t)blk * NS_ * DI_ + d;
#pragma unroll
  for (int n = 0; n < NS_; ++n) {
    Pbuf[ob + (size_t)n * DI_] = P[n];
    Sbuf[ob + (size_t)n * DI_] = S[n];
  }
}

// ---------------------------------------------------------------------------
// K5b: chunk-level scan -> h_in for each chunk.
// ---------------------------------------------------------------------------
__global__ void __launch_bounds__(192) k_scan2(
    const float* __restrict__ Pbuf, const float* __restrict__ Sbuf,
    float* __restrict__ Hin) {
  int bk = blockIdx.x;
  int d = threadIdx.x;
  float h[NS_];
#pragma unroll
  for (int n = 0; n < NS_; ++n) h[n] = 0.f;
  for (int c = 0; c < C_; ++c) {
    size_t base = ((size_t)(bk * C_ + c) * NS_) * DI_ + d;
#pragma unroll
    for (int n = 0; n < NS_; ++n) {
      size_t i = base + (size_t)n * DI_;
      Hin[i] = h[n];
      h[n] = Pbuf[i] * h[n] + Sbuf[i];
    }
  }
}

// ---------------------------------------------------------------------------
// K5c: chunked scan pass 3 — recompute recurrence from h_in, emit out_y.
// ---------------------------------------------------------------------------
__global__ void __launch_bounds__(192) k_scan3(
    const float* __restrict__ delta, const float* __restrict__ xs,
    const float* __restrict__ Bsb, const float* __restrict__ Csb,
    const float* __restrict__ A_logs, const float* __restrict__ Ds,
    const float* __restrict__ Hin, float* __restrict__ out_y) {
  int blk = blockIdx.x;            // bk*C_ + c
  int bk = blk / C_, c = blk % C_;
  int k = bk % K_;
  int d = threadIdx.x;
  float A[NS_];
#pragma unroll
  for (int n = 0; n < NS_; ++n) A[n] = -expf(A_logs[((size_t)k * DI_ + d) * NS_ + n]);
  float Dk = Ds[k * DI_ + d];
  float h[NS_];
  size_t hb = (size_t)blk * NS_ * DI_ + d;
#pragma unroll
  for (int n = 0; n < NS_; ++n) h[n] = Hin[hb + (size_t)n * DI_];
  size_t base = (size_t)bk * L_ + (size_t)c * LC_;
  for (int l = 0; l < LC_; ++l) {
    float dl = delta[(base + l) * DI_ + d];
    float u = xs[(base + l) * DI_ + d];
    float du = dl * u;
    const float* Bp = Bsb + (base + l) * NS_;
    const float* Cp = Csb + (base + l) * NS_;
    float yacc = 0.f;
#pragma unroll
    for (int n = 0; n < NS_; ++n) {
      h[n] = expf(dl * A[n]) * h[n] + du * Bp[n];
      yacc += h[n] * Cp[n];
    }
    out_y[(base + l) * DI_ + d] = yacc + Dk * u;
  }
}

// ---------------------------------------------------------------------------
// K6a: merge directions + LayerNorm (single pass sum/sumsq) + gate -> gv.
// grid = B*L blocks, 192 threads; all 3 heads per block.
// ---------------------------------------------------------------------------
__global__ void __launch_bounds__(192) k_merge_ln(
    const float* __restrict__ out_y, const float* __restrict__ zg,
    const float* __restrict__ lnw, const float* __restrict__ lnb,
    float* __restrict__ gv) {
  int bl = blockIdx.x;
  int b = bl / L_, lp = bl % L_;
  int h = lp / W_, w = lp % W_;
  int d = threadIdx.x;
  int wave = d >> 6, lane = d & 63;
  float zgv = zg[(size_t)bl * DI_ + d];
  float gw = lnw[d], gb2 = lnb[d];
  __shared__ float wsum[3], wsq[3];
#pragma unroll
  for (int m = 0; m < 3; ++m) {
    int l0;
    if (m == 0) l0 = lp;
    else if (m == 1) l0 = w * H_ + h;
    else l0 = ((w - h + W_) % W_) * H_ + h;
    size_t basef = ((size_t)b * K_ + m) * L_;
    size_t baser = ((size_t)b * K_ + m + 3) * L_;
    float t = out_y[(basef + l0) * DI_ + d] + out_y[(baser + (L_ - 1 - l0)) * DI_ + d];
    float s = t, s2 = t * t;
#pragma unroll
    for (int off = 32; off; off >>= 1) {
      s += __shfl_down(s, off, 64);
      s2 += __shfl_down(s2, off, 64);
    }
    __syncthreads();              // prior iteration's reads of wsum done
    if (lane == 0) { wsum[wave] = s; wsq[wave] = s2; }
    __syncthreads();
    float sum = wsum[0] + wsum[1] + wsum[2];
    float sum2 = wsq[0] + wsq[1] + wsq[2];
    float mu = sum * (1.f / DI_);
    float var = fmaxf(sum2 * (1.f / DI_) - mu * mu, 0.f);
    float g = (t - mu) * rsqrtf(var + 1e-5f) * gw + gb2;
    gv[((size_t)m * (B_ * L_) + bl) * DI_ + d] = g * zgv;
  }
}

// ---------------------------------------------------------------------------
// transpose out_proj_w (96x192) -> wT (192x96)
// ---------------------------------------------------------------------------
__global__ void k_wt(const float* __restrict__ opw, float* __restrict__ wT) {
  int c = blockIdx.x;      // 0..191
  int o = threadIdx.x;     // 0..95
  wT[(size_t)c * DM_ + o] = opw[(size_t)o * DI_ + c];
}

// ---------------------------------------------------------------------------
// K6b: out-proj tiled GEMM.  C[M=13824][96] = gv[M][192] * wT[192][96]
// block: 256 threads, tile 64(M) x 96(N), K-chunks of 32.  grid = 216.
// ---------------------------------------------------------------------------
constexpr int BM = 64, BK = 32;
__global__ void __launch_bounds__(256) k_outproj(
    const float* __restrict__ gv, const float* __restrict__ wT,
    float* __restrict__ out) {
  __shared__ float As[BM][BK + 1];
  __shared__ float Ws[BK][DM_ + 1];
  int tid = threadIdx.x;
  int tm = tid >> 4, tn = tid & 15;   // 16 x 16
  int pos0 = blockIdx.x * BM;
  float acc[4][6];
#pragma unroll
  for (int i = 0; i < 4; ++i)
#pragma unroll
    for (int j = 0; j < 6; ++j) acc[i][j] = 0.f;

  for (int k0 = 0; k0 < DI_; k0 += BK) {
    // stage A: 64 rows x 32 cols = 512 float4, 2 per thread
#pragma unroll
    for (int it = 0; it < 2; ++it) {
      int i = tid + it * 256;
      int r = i >> 3, c4 = (i & 7) << 2;
      const float4 v = *reinterpret_cast<const float4*>(
          &gv[(size_t)(pos0 + r) * DI_ + k0 + c4]);
      As[r][c4] = v.x; As[r][c4 + 1] = v.y; As[r][c4 + 2] = v.z; As[r][c4 + 3] = v.w;
    }
    // stage W: 32 rows x 96 cols = 768 float4 / 4 = ... 32*24 = 768 float4? no:
    // 32*96/4 = 768 float4, 3 per thread
#pragma unroll
    for (int it = 0; it < 3; ++it) {
      int i = tid + it * 256;
      int r = i / 24, c4 = (i % 24) << 2;
      const float4 v = *reinterpret_cast<const float4*>(
          &wT[(size_t)(k0 + r) * DM_ + c4]);
      Ws[r][c4] = v.x; Ws[r][c4 + 1] = v.y; Ws[r][c4 + 2] = v.z; Ws[r][c4 + 3] = v.w;
    }
    __syncthreads();
#pragma unroll
    for (int kk = 0; kk < BK; ++kk) {
      float a0 = As[tm * 4 + 0][kk], a1 = As[tm * 4 + 1][kk];
      float a2 = As[tm * 4 + 2][kk], a3 = As[tm * 4 + 3][kk];
      float w[6];
#pragma unroll
      for (int j = 0; j < 6; ++j) w[j] = Ws[kk][tn * 6 + j];
#pragma unroll
      for (int j = 0; j < 6; ++j) {
        acc[0][j] += a0 * w[j];
        acc[1][j] += a1 * w[j];
        acc[2][j] += a2 * w[j];
        acc[3][j] += a3 * w[j];
      }
    }
    __syncthreads();
  }
#pragma unroll
  for (int i = 0; i < 4; ++i) {
    size_t ob = (size_t)(pos0 + tm * 4 + i) * DM_ + tn * 6;
#pragma unroll
    for (int j = 0; j < 6; ++j) out[ob + j] = acc[i][j];
  }
}

}  // namespace

extern "C" void kernel_launch(void* const* d_in, const int* in_sizes, int n_in,
                              void* d_out, int out_size, void* d_ws, size_t ws_size,
                              hipStream_t stream) {
  const float* x = (const float*)d_in[0];
  const float* y = (const float*)d_in[1];
  const float* kin = (const float*)d_in[2];
  const float* in_proj_w = (const float*)d_in[3];
  const float* conv_w = (const float*)d_in[4];
  const float* conv_b = (const float*)d_in[5];
  const float* x_proj_w = (const float*)d_in[6];
  const float* dt_w = (const float*)d_in[7];
  const float* dt_b = (const float*)d_in[8];
  const float* A_logs = (const float*)d_in[9];
  const float* Ds = (const float*)d_in[10];
  const float* ln_w = (const float*)d_in[11];
  const float* ln_b = (const float*)d_in[12];
  const float* out_proj_w = (const float*)d_in[13];
  float* out = (float*)d_out;

  float* ws = (float*)d_ws;
  const size_t BLD = (size_t)B_ * L_ * DI_;                 // 884736
  const size_t BKLD = (size_t)B_ * K_ * L_ * DI_;           // 5308416
  const size_t BKLN = (size_t)B_ * K_ * L_ * NS_;           // 442368
  const size_t PSN = (size_t)B_ * K_ * C_ * NS_ * DI_;      // 1769472
  float* xv = ws;             ws += BLD;
  float* yv = ws;             ws += BLD;
  float* zg = ws;             ws += BLD;
  float* xc = ws;             ws += BLD;
  float* yc = ws;             ws += BLD;
  float* xs = ws;             ws += BKLD;
  float* delta = ws;          ws += BKLD;
  float* Bsb = ws;            ws += BKLN;
  float* Csb = ws;            ws += BKLN;
  float* out_y = ws;          ws += BKLD;
  float* Hin = ws;            ws += PSN;
  float* wT = ws;             ws += (size_t)DI_ * DM_;
  // aliases onto dead regions:
  float* Pbuf = xv;    // spans xv+yv  (2*BLD == PSN), dead after build_xs
  float* Sbuf = xc;    // spans xc+yc
  float* gv = delta;   // 3*B*L*DI <= BKLD, delta dead after scan3

  dim3 blk(DI_);
  k_wt<<<DI_, DM_, 0, stream>>>(out_proj_w, wT);
  k_inproj<<<B_ * L_, blk, 0, stream>>>(x, y, kin, in_proj_w, xv, yv, zg);
  k_conv<<<B_ * L_, blk, 0, stream>>>(xv, conv_w, conv_b, xc);
  k_conv<<<B_ * L_, blk, 0, stream>>>(yv, conv_w, conv_b, yc);
  k_build_xs<<<B_ * L_, blk, 0, stream>>>(xc, yc, xs);
  k_xdbl<<<B_ * K_ * L_, blk, 0, stream>>>(xs, x_proj_w, dt_w, dt_b, delta, Bsb, Csb);
  k_scan1<<<B_ * K_ * C_, blk, 0, stream>>>(delta, xs, Bsb, A_logs, Pbuf, Sbuf);
  k_scan2<<<B_ * K_, blk, 0, stream>>>(Pbuf, Sbuf, Hin);
  k_scan3<<<B_ * K_ * C_, blk, 0, stream>>>(delta, xs, Bsb, Csb, A_logs, Ds, Hin, out_y);
  k_merge_ln<<<B_ * L_, blk, 0, stream>>>(out_y, zg, ln_w, ln_b, gv);
  k_outproj<<<3 * B_ * L_ / BM, 256, 0, stream>>>(gv, wT, out);
}

// Round 4
// 396.375 us; speedup vs baseline: 6.6791x; 1.0960x over previous
//
#include <hip/hip_runtime.h>
#include <hip/hip_bf16.h>

namespace {

constexpr int B_ = 2, H_ = 48, W_ = 48, DM_ = 96, DI_ = 192, NS_ = 16, RK_ = 6, K_ = 6;
constexpr int L_ = H_ * W_;
constexpr int C_ = 48;            // chunks per (b,k) stream
constexpr int LC_ = L_ / C_;      // 48 steps per chunk
constexpr int NPROJ = RK_ + 2 * NS_;  // 38
constexpr int NPAD = 48;              // padded N for the xdbl GEMM

__device__ __forceinline__ float sigmoidf_(float x) { return 1.f / (1.f + expf(-x)); }

// ---------------------------------------------------------------------------
// K1: in_proj for x,y (first DI rows) and z-gate (rows DI..2DI) + SiLU(z)
// ---------------------------------------------------------------------------
__global__ void k_inproj(const float* __restrict__ x, const float* __restrict__ y,
                         const float* __restrict__ kin, const float* __restrict__ Wp,
                         float* __restrict__ xv, float* __restrict__ yv,
                         float* __restrict__ zg) {
  int bl = blockIdx.x;
  int d = threadIdx.x;
  __shared__ float sx[DM_], sy[DM_], sk[DM_];
  if (d < DM_) {
    sx[d] = x[(size_t)bl * DM_ + d];
    sy[d] = y[(size_t)bl * DM_ + d];
    sk[d] = kin[(size_t)bl * DM_ + d];
  }
  __syncthreads();
  const float* w1 = Wp + (size_t)d * DM_;
  const float* w2 = Wp + (size_t)(DI_ + d) * DM_;
  float ax = 0.f, ay = 0.f, az = 0.f;
#pragma unroll 8
  for (int c = 0; c < DM_; ++c) {
    float w = w1[c];
    ax += sx[c] * w;
    ay += sy[c] * w;
    az += sk[c] * w2[c];
  }
  xv[(size_t)bl * DI_ + d] = ax;
  yv[(size_t)bl * DI_ + d] = ay;
  zg[(size_t)bl * DI_ + d] = az * sigmoidf_(az);
}

// ---------------------------------------------------------------------------
// K2: depthwise 3x3 conv (pad 1) + bias + SiLU.  layout (B, L, DI)
// ---------------------------------------------------------------------------
__global__ void k_conv(const float* __restrict__ in, const float* __restrict__ cw,
                       const float* __restrict__ cb, float* __restrict__ out) {
  int bl = blockIdx.x;
  int d = threadIdx.x;
  int b = bl / L_, l = bl % L_;
  int h = l / W_, w = l % W_;
  float acc = cb[d];
  const float* wp = cw + d * 9;
#pragma unroll
  for (int kh = 0; kh < 3; ++kh) {
    int hh = h + kh - 1;
    if (hh < 0 || hh >= H_) continue;
#pragma unroll
    for (int kw = 0; kw < 3; ++kw) {
      int ww = w + kw - 1;
      if (ww < 0 || ww >= W_) continue;
      acc += in[((size_t)b * L_ + hh * W_ + ww) * DI_ + d] * wp[kh * 3 + kw];
    }
  }
  out[(size_t)bl * DI_ + d] = acc * sigmoidf_(acc);
}

// ---------------------------------------------------------------------------
// K3: build the 6 direction streams xs in (B, K, L, D) layout.
// ---------------------------------------------------------------------------
__global__ void k_build_xs(const float* __restrict__ xc, const float* __restrict__ yc,
                           float* __restrict__ xs) {
  int bl = blockIdx.x;
  int d = threadIdx.x;
  int b = bl / L_, l = bl % L_;
  int h = l / W_, w = l % W_;
  float vx = xc[(size_t)bl * DI_ + d];
  float vy = yc[(size_t)bl * DI_ + d];
  float vd = yc[((size_t)b * L_ + h * W_ + (h + w) % W_) * DI_ + d];
  size_t base = (size_t)b * K_ * L_;
  int lv = w * H_ + h;
  xs[(base + (size_t)0 * L_ + l) * DI_ + d] = vx;
  xs[(base + (size_t)1 * L_ + lv) * DI_ + d] = vy;
  xs[(base + (size_t)2 * L_ + lv) * DI_ + d] = vd;
  xs[(base + (size_t)3 * L_ + (L_ - 1 - l)) * DI_ + d] = vx;
  xs[(base + (size_t)4 * L_ + (L_ - 1 - lv)) * DI_ + d] = vy;
  xs[(base + (size_t)5 * L_ + (L_ - 1 - lv)) * DI_ + d] = vd;
}

// ---------------------------------------------------------------------------
// transpose+pad x_proj_w: xpwT[k][dd][c] = xpw[k][c][dd]  (c<38, else 0)
// grid = K_, block = 192 (dd)
// ---------------------------------------------------------------------------
__global__ void k_xpwT(const float* __restrict__ xpw, float* __restrict__ xpwT) {
  int k = blockIdx.x;
  int dd = threadIdx.x;
  float* dst = xpwT + ((size_t)k * DI_ + dd) * NPAD;
  for (int c = 0; c < NPAD; ++c)
    dst[c] = (c < NPROJ) ? xpw[((size_t)k * NPROJ + c) * DI_ + dd] : 0.f;
}

// ---------------------------------------------------------------------------
// K4: x_dbl GEMM + delta/Bs/Cs epilogue.
// M = B*K*L rows (tiles of XM=64, within one k), N = 38 (pad 48), K = 192.
// block 256 threads; grid = B*K*L/64 = 432.
// ---------------------------------------------------------------------------
constexpr int XM = 64, XBK = 32;
__global__ void __launch_bounds__(256) k_xdbl2(
    const float* __restrict__ xs, const float* __restrict__ xpwT,
    const float* __restrict__ dtw, const float* __restrict__ dtb,
    float* __restrict__ delta, float* __restrict__ Bsb, float* __restrict__ Csb) {
  __shared__ float As[XM][XBK + 1];
  __shared__ float Ws[XBK][NPAD];
  __shared__ float xd[XM][NPAD + 1];
  __shared__ float dtws[DI_ * RK_];
  __shared__ float dtbs[DI_];
  int tid = threadIdx.x;
  int row0 = blockIdx.x * XM;
  int k = (row0 / L_) % K_;

  // stage dt weights for this k
  for (int i = tid; i < DI_ * RK_; i += 256) dtws[i] = dtw[(size_t)k * DI_ * RK_ + i];
  if (tid < DI_) dtbs[tid] = dtb[k * DI_ + tid];

  int tm = tid >> 4, tn = tid & 15;   // 16 x 16
  float acc[4][3];
#pragma unroll
  for (int i = 0; i < 4; ++i)
#pragma unroll
    for (int j = 0; j < 3; ++j) acc[i][j] = 0.f;

  for (int k0 = 0; k0 < DI_; k0 += XBK) {
    // stage A: 64 rows x 32 cols = 512 float4, 2 per thread
#pragma unroll
    for (int it = 0; it < 2; ++it) {
      int i = tid + it * 256;
      int r = i >> 3, c4 = (i & 7) << 2;
      const float4 v = *reinterpret_cast<const float4*>(
          &xs[(size_t)(row0 + r) * DI_ + k0 + c4]);
      As[r][c4] = v.x; As[r][c4 + 1] = v.y; As[r][c4 + 2] = v.z; As[r][c4 + 3] = v.w;
    }
    // stage W: 32 rows x 48 cols = 384 float4
#pragma unroll
    for (int it = 0; it < 2; ++it) {
      int i = tid + it * 256;
      if (i < (XBK * NPAD) / 4) {
        int r = i / (NPAD / 4), c4 = (i % (NPAD / 4)) << 2;
        const float4 v = *reinterpret_cast<const float4*>(
            &xpwT[((size_t)k * DI_ + k0 + r) * NPAD + c4]);
        Ws[r][c4] = v.x; Ws[r][c4 + 1] = v.y; Ws[r][c4 + 2] = v.z; Ws[r][c4 + 3] = v.w;
      }
    }
    __syncthreads();
#pragma unroll
    for (int kk = 0; kk < XBK; ++kk) {
      float a0 = As[tm * 4 + 0][kk], a1 = As[tm * 4 + 1][kk];
      float a2 = As[tm * 4 + 2][kk], a3 = As[tm * 4 + 3][kk];
      float w0 = Ws[kk][tn * 3 + 0], w1 = Ws[kk][tn * 3 + 1], w2 = Ws[kk][tn * 3 + 2];
      acc[0][0] += a0 * w0; acc[0][1] += a0 * w1; acc[0][2] += a0 * w2;
      acc[1][0] += a1 * w0; acc[1][1] += a1 * w1; acc[1][2] += a1 * w2;
      acc[2][0] += a2 * w0; acc[2][1] += a2 * w1; acc[2][2] += a2 * w2;
      acc[3][0] += a3 * w0; acc[3][1] += a3 * w1; acc[3][2] += a3 * w2;
    }
    __syncthreads();
  }
  // spill result tile to LDS
#pragma unroll
  for (int i = 0; i < 4; ++i)
#pragma unroll
    for (int j = 0; j < 3; ++j) xd[tm * 4 + i][tn * 3 + j] = acc[i][j];
  __syncthreads();

  // epilogue 1: Bs / Cs  (64 rows x 16 each)
  for (int i = tid; i < XM * NS_; i += 256) {
    int r = i >> 4, n = i & 15;
    Bsb[(size_t)(row0 + r) * NS_ + n] = xd[r][RK_ + n];
    Csb[(size_t)(row0 + r) * NS_ + n] = xd[r][RK_ + NS_ + n];
  }
  // epilogue 2: delta (64 rows x 192)
  for (int i = tid; i < XM * DI_; i += 256) {
    int r = i / DI_, d = i % DI_;
    float s = dtbs[d];
    const float* dwp = dtws + d * RK_;
#pragma unroll
    for (int rr = 0; rr < RK_; ++rr) s += xd[r][rr] * dwp[rr];
    float dl = (s > 20.f) ? s : log1pf(expf(s));
    delta[(size_t)(row0 + r) * DI_ + d] = dl;
  }
}

// ---------------------------------------------------------------------------
// K5a: chunked scan pass 1 — per-chunk transition product P, zero-input S.
// ---------------------------------------------------------------------------
__global__ void __launch_bounds__(192) k_scan1(
    const float* __restrict__ delta, const float* __restrict__ xs,
    const float* __restrict__ Bsb, const float* __restrict__ A_logs,
    float* __restrict__ Pbuf, float* __restrict__ Sbuf) {
  int blk = blockIdx.x;            // bk*C_ + c
  int bk = blk / C_, c = blk % C_;
  int k = bk % K_;
  int d = threadIdx.x;
  float A[NS_];
#pragma unroll
  for (int n = 0; n < NS_; ++n) A[n] = -expf(A_logs[((size_t)k * DI_ + d) * NS_ + n]);
  float P[NS_], S[NS_];
#pragma unroll
  for (int n = 0; n < NS_; ++n) { P[n] = 1.f; S[n] = 0.f; }
  size_t base = (size_t)bk * L_ + (size_t)c * LC_;
  for (int l = 0; l < LC_; ++l) {
    float dl = delta[(base + l) * DI_ + d];
    float u = xs[(base + l) * DI_ + d];
    float du = dl * u;
    const float* Bp = Bsb + (base + l) * NS_;
#pragma unroll
    for (int n = 0; n < NS_; ++n) {
      float e = expf(dl * A[n]);
      S[n] = e * S[n] + du * Bp[n];
      P[n] *= e;
    }
  }
  size_t ob = (size_t)blk * NS_ * DI_ + d;
#pragma unroll
  for (int n = 0; n < NS_; ++n) {
    Pbuf[ob + (size_t)n * DI_] = P[n];
    Sbuf[ob + (size_t)n * DI_] = S[n];
  }
}

// ---------------------------------------------------------------------------
// K5b: chunk-level scan -> h_in for each chunk.
// ---------------------------------------------------------------------------
__global__ void __launch_bounds__(192) k_scan2(
    const float* __restrict__ Pbuf, const float* __restrict__ Sbuf,
    float* __restrict__ Hin) {
  int bk = blockIdx.x;
  int d = threadIdx.x;
  float h[NS_];
#pragma unroll
  for (int n = 0; n < NS_; ++n) h[n] = 0.f;
  for (int c = 0; c < C_; ++c) {
    size_t base = ((size_t)(bk * C_ + c) * NS_) * DI_ + d;
#pragma unroll
    for (int n = 0; n < NS_; ++n) {
      size_t i = base + (size_t)n * DI_;
      Hin[i] = h[n];
      h[n] = Pbuf[i] * h[n] + Sbuf[i];
    }
  }
}

// ---------------------------------------------------------------------------
// K5c: chunked scan pass 3 — recompute recurrence from h_in, emit out_y.
// ---------------------------------------------------------------------------
__global__ void __launch_bounds__(192) k_scan3(
    const float* __restrict__ delta, const float* __restrict__ xs,
    const float* __restrict__ Bsb, const float* __restrict__ Csb,
    const float* __restrict__ A_logs, const float* __restrict__ Ds,
    const float* __restrict__ Hin, float* __restrict__ out_y) {
  int blk = blockIdx.x;            // bk*C_ + c
  int bk = blk / C_, c = blk % C_;
  int k = bk % K_;
  int d = threadIdx.x;
  float A[NS_];
#pragma unroll
  for (int n = 0; n < NS_; ++n) A[n] = -expf(A_logs[((size_t)k * DI_ + d) * NS_ + n]);
  float Dk = Ds[k * DI_ + d];
  float h[NS_];
  size_t hb = (size_t)blk * NS_ * DI_ + d;
#pragma unroll
  for (int n = 0; n < NS_; ++n) h[n] = Hin[hb + (size_t)n * DI_];
  size_t base = (size_t)bk * L_ + (size_t)c * LC_;
  for (int l = 0; l < LC_; ++l) {
    float dl = delta[(base + l) * DI_ + d];
    float u = xs[(base + l) * DI_ + d];
    float du = dl * u;
    const float* Bp = Bsb + (base + l) * NS_;
    const float* Cp = Csb + (base + l) * NS_;
    float yacc = 0.f;
#pragma unroll
    for (int n = 0; n < NS_; ++n) {
      h[n] = expf(dl * A[n]) * h[n] + du * Bp[n];
      yacc += h[n] * Cp[n];
    }
    out_y[(base + l) * DI_ + d] = yacc + Dk * u;
  }
}

// ---------------------------------------------------------------------------
// K6a: merge directions + LayerNorm (single pass sum/sumsq) + gate -> gv.
// ---------------------------------------------------------------------------
__global__ void __launch_bounds__(192) k_merge_ln(
    const float* __restrict__ out_y, const float* __restrict__ zg,
    const float* __restrict__ lnw, const float* __restrict__ lnb,
    float* __restrict__ gv) {
  int bl = blockIdx.x;
  int b = bl / L_, lp = bl % L_;
  int h = lp / W_, w = lp % W_;
  int d = threadIdx.x;
  int wave = d >> 6, lane = d & 63;
  float zgv = zg[(size_t)bl * DI_ + d];
  float gw = lnw[d], gb2 = lnb[d];
  __shared__ float wsum[3], wsq[3];
#pragma unroll
  for (int m = 0; m < 3; ++m) {
    int l0;
    if (m == 0) l0 = lp;
    else if (m == 1) l0 = w * H_ + h;
    else l0 = ((w - h + W_) % W_) * H_ + h;
    size_t basef = ((size_t)b * K_ + m) * L_;
    size_t baser = ((size_t)b * K_ + m + 3) * L_;
    float t = out_y[(basef + l0) * DI_ + d] + out_y[(baser + (L_ - 1 - l0)) * DI_ + d];
    float s = t, s2 = t * t;
#pragma unroll
    for (int off = 32; off; off >>= 1) {
      s += __shfl_down(s, off, 64);
      s2 += __shfl_down(s2, off, 64);
    }
    __syncthreads();
    if (lane == 0) { wsum[wave] = s; wsq[wave] = s2; }
    __syncthreads();
    float sum = wsum[0] + wsum[1] + wsum[2];
    float sum2 = wsq[0] + wsq[1] + wsq[2];
    float mu = sum * (1.f / DI_);
    float var = fmaxf(sum2 * (1.f / DI_) - mu * mu, 0.f);
    float g = (t - mu) * rsqrtf(var + 1e-5f) * gw + gb2;
    gv[((size_t)m * (B_ * L_) + bl) * DI_ + d] = g * zgv;
  }
}

// ---------------------------------------------------------------------------
// transpose out_proj_w (96x192) -> wT (192x96)
// ---------------------------------------------------------------------------
__global__ void k_wt(const float* __restrict__ opw, float* __restrict__ wT) {
  int c = blockIdx.x;
  int o = threadIdx.x;
  wT[(size_t)c * DM_ + o] = opw[(size_t)o * DI_ + c];
}

// ---------------------------------------------------------------------------
// K6b: out-proj tiled GEMM.  C[M=13824][96] = gv[M][192] * wT[192][96]
// ---------------------------------------------------------------------------
constexpr int BM = 64, BK = 32;
__global__ void __launch_bounds__(256) k_outproj(
    const float* __restrict__ gv, const float* __restrict__ wT,
    float* __restrict__ out) {
  __shared__ float As[BM][BK + 1];
  __shared__ float Ws[BK][DM_ + 1];
  int tid = threadIdx.x;
  int tm = tid >> 4, tn = tid & 15;
  int pos0 = blockIdx.x * BM;
  float acc[4][6];
#pragma unroll
  for (int i = 0; i < 4; ++i)
#pragma unroll
    for (int j = 0; j < 6; ++j) acc[i][j] = 0.f;

  for (int k0 = 0; k0 < DI_; k0 += BK) {
#pragma unroll
    for (int it = 0; it < 2; ++it) {
      int i = tid + it * 256;
      int r = i >> 3, c4 = (i & 7) << 2;
      const float4 v = *reinterpret_cast<const float4*>(
          &gv[(size_t)(pos0 + r) * DI_ + k0 + c4]);
      As[r][c4] = v.x; As[r][c4 + 1] = v.y; As[r][c4 + 2] = v.z; As[r][c4 + 3] = v.w;
    }
#pragma unroll
    for (int it = 0; it < 3; ++it) {
      int i = tid + it * 256;
      int r = i / 24, c4 = (i % 24) << 2;
      const float4 v = *reinterpret_cast<const float4*>(
          &wT[(size_t)(k0 + r) * DM_ + c4]);
      Ws[r][c4] = v.x; Ws[r][c4 + 1] = v.y; Ws[r][c4 + 2] = v.z; Ws[r][c4 + 3] = v.w;
    }
    __syncthreads();
#pragma unroll
    for (int kk = 0; kk < BK; ++kk) {
      float a0 = As[tm * 4 + 0][kk], a1 = As[tm * 4 + 1][kk];
      float a2 = As[tm * 4 + 2][kk], a3 = As[tm * 4 + 3][kk];
      float w[6];
#pragma unroll
      for (int j = 0; j < 6; ++j) w[j] = Ws[kk][tn * 6 + j];
#pragma unroll
      for (int j = 0; j < 6; ++j) {
        acc[0][j] += a0 * w[j];
        acc[1][j] += a1 * w[j];
        acc[2][j] += a2 * w[j];
        acc[3][j] += a3 * w[j];
      }
    }
    __syncthreads();
  }
#pragma unroll
  for (int i = 0; i < 4; ++i) {
    size_t ob = (size_t)(pos0 + tm * 4 + i) * DM_ + tn * 6;
#pragma unroll
    for (int j = 0; j < 6; ++j) out[ob + j] = acc[i][j];
  }
}

}  // namespace

extern "C" void kernel_launch(void* const* d_in, const int* in_sizes, int n_in,
                              void* d_out, int out_size, void* d_ws, size_t ws_size,
                              hipStream_t stream) {
  const float* x = (const float*)d_in[0];
  const float* y = (const float*)d_in[1];
  const float* kin = (const float*)d_in[2];
  const float* in_proj_w = (const float*)d_in[3];
  const float* conv_w = (const float*)d_in[4];
  const float* conv_b = (const float*)d_in[5];
  const float* x_proj_w = (const float*)d_in[6];
  const float* dt_w = (const float*)d_in[7];
  const float* dt_b = (const float*)d_in[8];
  const float* A_logs = (const float*)d_in[9];
  const float* Ds = (const float*)d_in[10];
  const float* ln_w = (const float*)d_in[11];
  const float* ln_b = (const float*)d_in[12];
  const float* out_proj_w = (const float*)d_in[13];
  float* out = (float*)d_out;

  float* ws = (float*)d_ws;
  const size_t BLD = (size_t)B_ * L_ * DI_;                 // 884736
  const size_t BKLD = (size_t)B_ * K_ * L_ * DI_;           // 5308416
  const size_t BKLN = (size_t)B_ * K_ * L_ * NS_;           // 442368
  const size_t PSN = (size_t)B_ * K_ * C_ * NS_ * DI_;      // 1769472
  float* xv = ws;             ws += BLD;
  float* yv = ws;             ws += BLD;
  float* zg = ws;             ws += BLD;
  float* xc = ws;             ws += BLD;
  float* yc = ws;             ws += BLD;
  float* xs = ws;             ws += BKLD;
  float* delta = ws;          ws += BKLD;
  float* Bsb = ws;            ws += BKLN;
  float* Csb = ws;            ws += BKLN;
  float* out_y = ws;          ws += BKLD;
  float* Hin = ws;            ws += PSN;
  float* wT = ws;             ws += (size_t)DI_ * DM_;
  float* xpwT = ws;           ws += (size_t)K_ * DI_ * NPAD;
  // aliases onto dead regions:
  float* Pbuf = xv;    // spans xv+yv  (2*BLD == PSN), dead after build_xs
  float* Sbuf = xc;    // spans xc+yc
  float* gv = delta;   // 3*B*L*DI <= BKLD, delta dead after scan3

  dim3 blk(DI_);
  k_wt<<<DI_, DM_, 0, stream>>>(out_proj_w, wT);
  k_xpwT<<<K_, DI_, 0, stream>>>(x_proj_w, xpwT);
  k_inproj<<<B_ * L_, blk, 0, stream>>>(x, y, kin, in_proj_w, xv, yv, zg);
  k_conv<<<B_ * L_, blk, 0, stream>>>(xv, conv_w, conv_b, xc);
  k_conv<<<B_ * L_, blk, 0, stream>>>(yv, conv_w, conv_b, yc);
  k_build_xs<<<B_ * L_, blk, 0, stream>>>(xc, yc, xs);
  k_xdbl2<<<B_ * K_ * L_ / XM, 256, 0, stream>>>(xs, xpwT, dt_w, dt_b, delta, Bsb, Csb);
  k_scan1<<<B_ * K_ * C_, blk, 0, stream>>>(delta, xs, Bsb, A_logs, Pbuf, Sbuf);
  k_scan2<<<B_ * K_, blk, 0, stream>>>(Pbuf, Sbuf, Hin);
  k_scan3<<<B_ * K_ * C_, blk, 0, stream>>>(delta, xs, Bsb, Csb, A_logs, Ds, Hin, out_y);
  k_merge_ln<<<B_ * L_, blk, 0, stream>>>(out_y, zg, ln_w, ln_b, gv);
  k_outproj<<<3 * B_ * L_ / BM, 256, 0, stream>>>(gv, wT, out);
}

// Round 5
// 243.355 us; speedup vs baseline: 10.8789x; 1.6288x over previous
//
#include <hip/hip_runtime.h>
#include <hip/hip_bf16.h>

namespace {

constexpr int B_ = 2, H_ = 48, W_ = 48, DM_ = 96, DI_ = 192, NS_ = 16, RK_ = 6, K_ = 6;
constexpr int L_ = H_ * W_;
constexpr int C_ = 96;            // chunks per (b,k) stream
constexpr int LC_ = L_ / C_;      // 24 steps per chunk
constexpr int NPROJ = RK_ + 2 * NS_;  // 38
constexpr int NPAD = 48;              // padded N for the xdbl GEMM

__device__ __forceinline__ float sigmoidf_(float x) { return 1.f / (1.f + expf(-x)); }

// ---------------------------------------------------------------------------
// transpose in_proj_w (384x96) -> wInT (96x384)
// ---------------------------------------------------------------------------
__global__ void k_wInT(const float* __restrict__ Wp, float* __restrict__ wInT) {
  int c = blockIdx.x;        // 0..95
  int o = threadIdx.x;       // 0..383
  wInT[(size_t)c * (2 * DI_) + o] = Wp[(size_t)o * DM_ + c];
}

// ---------------------------------------------------------------------------
// K1: in_proj as tiled GEMM.  Streams s=0(x->xv), 1(y->yv), 2(k->silu->zg).
// M = 3*B*L (tiles of 64 within one stream), N = 192, K = 96.
// grid = 216, block = 256.
// ---------------------------------------------------------------------------
constexpr int IM = 64, IBK = 32;
__global__ void __launch_bounds__(256) k_inproj2(
    const float* __restrict__ x, const float* __restrict__ y,
    const float* __restrict__ kin, const float* __restrict__ wInT,
    float* __restrict__ xv, float* __restrict__ yv, float* __restrict__ zg) {
  __shared__ float As[IM][IBK + 1];
  __shared__ float Ws[IBK][DI_ + 1];
  int tid = threadIdx.x;
  constexpr int BPS = (B_ * L_) / IM;   // 72 blocks per stream
  int s = blockIdx.x / BPS;
  int row0 = (blockIdx.x % BPS) * IM;
  const float* src = (s == 0) ? x : (s == 1) ? y : kin;
  float* dst = (s == 0) ? xv : (s == 1) ? yv : zg;
  int nbase = (s == 2) ? DI_ : 0;
  int tm = tid >> 4, tn = tid & 15;     // 16 x 16
  float acc[4][12];
#pragma unroll
  for (int i = 0; i < 4; ++i)
#pragma unroll
    for (int j = 0; j < 12; ++j) acc[i][j] = 0.f;

  for (int k0 = 0; k0 < DM_; k0 += IBK) {
    // A tile: 64 x 32 = 512 float4, 2/thread
#pragma unroll
    for (int it = 0; it < 2; ++it) {
      int i = tid + it * 256;
      int r = i >> 3, c4 = (i & 7) << 2;
      const float4 v = *reinterpret_cast<const float4*>(
          &src[(size_t)(row0 + r) * DM_ + k0 + c4]);
      As[r][c4] = v.x; As[r][c4 + 1] = v.y; As[r][c4 + 2] = v.z; As[r][c4 + 3] = v.w;
    }
    // W tile: 32 x 192 = 1536 float4, 6/thread
#pragma unroll
    for (int it = 0; it < 6; ++it) {
      int i = tid + it * 256;
      int r = i / 48, c4 = (i % 48) << 2;
      const float4 v = *reinterpret_cast<const float4*>(
          &wInT[(size_t)(k0 + r) * (2 * DI_) + nbase + c4]);
      Ws[r][c4] = v.x; Ws[r][c4 + 1] = v.y; Ws[r][c4 + 2] = v.z; Ws[r][c4 + 3] = v.w;
    }
    __syncthreads();
#pragma unroll
    for (int kk = 0; kk < IBK; ++kk) {
      float a[4];
#pragma unroll
      for (int i = 0; i < 4; ++i) a[i] = As[tm * 4 + i][kk];
      float w[12];
#pragma unroll
      for (int j = 0; j < 12; ++j) w[j] = Ws[kk][tn * 12 + j];
#pragma unroll
      for (int i = 0; i < 4; ++i)
#pragma unroll
        for (int j = 0; j < 12; ++j) acc[i][j] += a[i] * w[j];
    }
    __syncthreads();
  }
#pragma unroll
  for (int i = 0; i < 4; ++i) {
    size_t ob = (size_t)(row0 + tm * 4 + i) * DI_ + tn * 12;
#pragma unroll
    for (int j = 0; j < 12; ++j) {
      float v = acc[i][j];
      if (s == 2) v = v * sigmoidf_(v);
      dst[ob + j] = v;
    }
  }
}

// ---------------------------------------------------------------------------
// K2: depthwise 3x3 conv (pad 1) + bias + SiLU.  layout (B, L, DI)
// ---------------------------------------------------------------------------
__global__ void k_conv(const float* __restrict__ in, const float* __restrict__ cw,
                       const float* __restrict__ cb, float* __restrict__ out) {
  int bl = blockIdx.x;
  int d = threadIdx.x;
  int b = bl / L_, l = bl % L_;
  int h = l / W_, w = l % W_;
  float acc = cb[d];
  const float* wp = cw + d * 9;
#pragma unroll
  for (int kh = 0; kh < 3; ++kh) {
    int hh = h + kh - 1;
    if (hh < 0 || hh >= H_) continue;
#pragma unroll
    for (int kw = 0; kw < 3; ++kw) {
      int ww = w + kw - 1;
      if (ww < 0 || ww >= W_) continue;
      acc += in[((size_t)b * L_ + hh * W_ + ww) * DI_ + d] * wp[kh * 3 + kw];
    }
  }
  out[(size_t)bl * DI_ + d] = acc * sigmoidf_(acc);
}

// ---------------------------------------------------------------------------
// K3: build the 6 direction streams xs in (B, K, L, D) layout.
// ---------------------------------------------------------------------------
__global__ void k_build_xs(const float* __restrict__ xc, const float* __restrict__ yc,
                           float* __restrict__ xs) {
  int bl = blockIdx.x;
  int d = threadIdx.x;
  int b = bl / L_, l = bl % L_;
  int h = l / W_, w = l % W_;
  float vx = xc[(size_t)bl * DI_ + d];
  float vy = yc[(size_t)bl * DI_ + d];
  float vd = yc[((size_t)b * L_ + h * W_ + (h + w) % W_) * DI_ + d];
  size_t base = (size_t)b * K_ * L_;
  int lv = w * H_ + h;
  xs[(base + (size_t)0 * L_ + l) * DI_ + d] = vx;
  xs[(base + (size_t)1 * L_ + lv) * DI_ + d] = vy;
  xs[(base + (size_t)2 * L_ + lv) * DI_ + d] = vd;
  xs[(base + (size_t)3 * L_ + (L_ - 1 - l)) * DI_ + d] = vx;
  xs[(base + (size_t)4 * L_ + (L_ - 1 - lv)) * DI_ + d] = vy;
  xs[(base + (size_t)5 * L_ + (L_ - 1 - lv)) * DI_ + d] = vd;
}

// ---------------------------------------------------------------------------
// transpose+pad x_proj_w: xpwT[k][dd][c] = xpw[k][c][dd]  (c<38, else 0)
// ---------------------------------------------------------------------------
__global__ void k_xpwT(const float* __restrict__ xpw, float* __restrict__ xpwT) {
  int k = blockIdx.x;
  int dd = threadIdx.x;
  float* dst = xpwT + ((size_t)k * DI_ + dd) * NPAD;
  for (int c = 0; c < NPAD; ++c)
    dst[c] = (c < NPROJ) ? xpw[((size_t)k * NPROJ + c) * DI_ + dd] : 0.f;
}

// ---------------------------------------------------------------------------
// K4: x_dbl GEMM + delta/Bs/Cs epilogue.
// ---------------------------------------------------------------------------
constexpr int XM = 64, XBK = 32;
__global__ void __launch_bounds__(256) k_xdbl2(
    const float* __restrict__ xs, const float* __restrict__ xpwT,
    const float* __restrict__ dtw, const float* __restrict__ dtb,
    float* __restrict__ delta, float* __restrict__ Bsb, float* __restrict__ Csb) {
  __shared__ float As[XM][XBK + 1];
  __shared__ float Ws[XBK][NPAD];
  __shared__ float xd[XM][NPAD + 1];
  __shared__ float dtws[DI_ * RK_];
  __shared__ float dtbs[DI_];
  int tid = threadIdx.x;
  int row0 = blockIdx.x * XM;
  int k = (row0 / L_) % K_;

  for (int i = tid; i < DI_ * RK_; i += 256) dtws[i] = dtw[(size_t)k * DI_ * RK_ + i];
  if (tid < DI_) dtbs[tid] = dtb[k * DI_ + tid];

  int tm = tid >> 4, tn = tid & 15;
  float acc[4][3];
#pragma unroll
  for (int i = 0; i < 4; ++i)
#pragma unroll
    for (int j = 0; j < 3; ++j) acc[i][j] = 0.f;

  for (int k0 = 0; k0 < DI_; k0 += XBK) {
#pragma unroll
    for (int it = 0; it < 2; ++it) {
      int i = tid + it * 256;
      int r = i >> 3, c4 = (i & 7) << 2;
      const float4 v = *reinterpret_cast<const float4*>(
          &xs[(size_t)(row0 + r) * DI_ + k0 + c4]);
      As[r][c4] = v.x; As[r][c4 + 1] = v.y; As[r][c4 + 2] = v.z; As[r][c4 + 3] = v.w;
    }
#pragma unroll
    for (int it = 0; it < 2; ++it) {
      int i = tid + it * 256;
      if (i < (XBK * NPAD) / 4) {
        int r = i / (NPAD / 4), c4 = (i % (NPAD / 4)) << 2;
        const float4 v = *reinterpret_cast<const float4*>(
            &xpwT[((size_t)k * DI_ + k0 + r) * NPAD + c4]);
        Ws[r][c4] = v.x; Ws[r][c4 + 1] = v.y; Ws[r][c4 + 2] = v.z; Ws[r][c4 + 3] = v.w;
      }
    }
    __syncthreads();
#pragma unroll
    for (int kk = 0; kk < XBK; ++kk) {
      float a0 = As[tm * 4 + 0][kk], a1 = As[tm * 4 + 1][kk];
      float a2 = As[tm * 4 + 2][kk], a3 = As[tm * 4 + 3][kk];
      float w0 = Ws[kk][tn * 3 + 0], w1 = Ws[kk][tn * 3 + 1], w2 = Ws[kk][tn * 3 + 2];
      acc[0][0] += a0 * w0; acc[0][1] += a0 * w1; acc[0][2] += a0 * w2;
      acc[1][0] += a1 * w0; acc[1][1] += a1 * w1; acc[1][2] += a1 * w2;
      acc[2][0] += a2 * w0; acc[2][1] += a2 * w1; acc[2][2] += a2 * w2;
      acc[3][0] += a3 * w0; acc[3][1] += a3 * w1; acc[3][2] += a3 * w2;
    }
    __syncthreads();
  }
#pragma unroll
  for (int i = 0; i < 4; ++i)
#pragma unroll
    for (int j = 0; j < 3; ++j) xd[tm * 4 + i][tn * 3 + j] = acc[i][j];
  __syncthreads();

  for (int i = tid; i < XM * NS_; i += 256) {
    int r = i >> 4, n = i & 15;
    Bsb[(size_t)(row0 + r) * NS_ + n] = xd[r][RK_ + n];
    Csb[(size_t)(row0 + r) * NS_ + n] = xd[r][RK_ + NS_ + n];
  }
  for (int i = tid; i < XM * DI_; i += 256) {
    int r = i / DI_, d = i % DI_;
    float s = dtbs[d];
    const float* dwp = dtws + d * RK_;
#pragma unroll
    for (int rr = 0; rr < RK_; ++rr) s += xd[r][rr] * dwp[rr];
    float dl = (s > 20.f) ? s : log1pf(expf(s));
    delta[(size_t)(row0 + r) * DI_ + d] = dl;
  }
}

// ---------------------------------------------------------------------------
// K5a: chunked scan pass 1.  P via exp(A*sum_dl); S via fast-exp recurrence.
// grid = B*K*C_ = 1152, 192 threads.
// ---------------------------------------------------------------------------
__global__ void __launch_bounds__(192) k_scan1(
    const float* __restrict__ delta, const float* __restrict__ xs,
    const float* __restrict__ Bsb, const float* __restrict__ A_logs,
    float* __restrict__ Pbuf, float* __restrict__ SHin) {
  int blk = blockIdx.x;            // bk*C_ + c
  int bk = blk / C_, c = blk % C_;
  int k = bk % K_;
  int d = threadIdx.x;
  float A[NS_];
#pragma unroll
  for (int n = 0; n < NS_; ++n) A[n] = -expf(A_logs[((size_t)k * DI_ + d) * NS_ + n]);
  float S[NS_];
#pragma unroll
  for (int n = 0; n < NS_; ++n) S[n] = 0.f;
  float sum_dl = 0.f;
  size_t base = (size_t)bk * L_ + (size_t)c * LC_;
  for (int l = 0; l < LC_; ++l) {
    float dl = delta[(base + l) * DI_ + d];
    float u = xs[(base + l) * DI_ + d];
    float du = dl * u;
    sum_dl += dl;
    const float* Bp = Bsb + (base + l) * NS_;
#pragma unroll
    for (int n = 0; n < NS_; ++n) {
      float e = __expf(dl * A[n]);
      S[n] = e * S[n] + du * Bp[n];
    }
  }
  size_t ob = (size_t)blk * NS_ * DI_ + d;
#pragma unroll
  for (int n = 0; n < NS_; ++n) {
    Pbuf[ob + (size_t)n * DI_] = __expf(A[n] * sum_dl);
    SHin[ob + (size_t)n * DI_] = S[n];
  }
}

// ---------------------------------------------------------------------------
// K5b: chunk-level scan; SHin holds S on entry, h_in on exit (in-place).
// ---------------------------------------------------------------------------
__global__ void __launch_bounds__(192) k_scan2(
    const float* __restrict__ Pbuf, float* __restrict__ SHin) {
  int bk = blockIdx.x;
  int d = threadIdx.x;
  float h[NS_];
#pragma unroll
  for (int n = 0; n < NS_; ++n) h[n] = 0.f;
  for (int c = 0; c < C_; ++c) {
    size_t base = ((size_t)(bk * C_ + c) * NS_) * DI_ + d;
#pragma unroll
    for (int n = 0; n < NS_; ++n) {
      size_t i = base + (size_t)n * DI_;
      float s = SHin[i];
      float p = Pbuf[i];
      SHin[i] = h[n];
      h[n] = p * h[n] + s;
    }
  }
}

// ---------------------------------------------------------------------------
// K5c: chunked scan pass 3 — recompute from h_in, emit out_y.
// ---------------------------------------------------------------------------
__global__ void __launch_bounds__(192) k_scan3(
    const float* __restrict__ delta, const float* __restrict__ xs,
    const float* __restrict__ Bsb, const float* __restrict__ Csb,
    const float* __restrict__ A_logs, const float* __restrict__ Ds,
    const float* __restrict__ SHin, float* __restrict__ out_y) {
  int blk = blockIdx.x;            // bk*C_ + c
  int bk = blk / C_, c = blk % C_;
  int k = bk % K_;
  int d = threadIdx.x;
  float A[NS_];
#pragma unroll
  for (int n = 0; n < NS_; ++n) A[n] = -expf(A_logs[((size_t)k * DI_ + d) * NS_ + n]);
  float Dk = Ds[k * DI_ + d];
  float h[NS_];
  size_t hb = (size_t)blk * NS_ * DI_ + d;
#pragma unroll
  for (int n = 0; n < NS_; ++n) h[n] = SHin[hb + (size_t)n * DI_];
  size_t base = (size_t)bk * L_ + (size_t)c * LC_;
  for (int l = 0; l < LC_; ++l) {
    float dl = delta[(base + l) * DI_ + d];
    float u = xs[(base + l) * DI_ + d];
    float du = dl * u;
    const float* Bp = Bsb + (base + l) * NS_;
    const float* Cp = Csb + (base + l) * NS_;
    float yacc = 0.f;
#pragma unroll
    for (int n = 0; n < NS_; ++n) {
      h[n] = __expf(dl * A[n]) * h[n] + du * Bp[n];
      yacc += h[n] * Cp[n];
    }
    out_y[(base + l) * DI_ + d] = yacc + Dk * u;
  }
}

// ---------------------------------------------------------------------------
// K6a: merge directions + LayerNorm + gate -> gv.
// ---------------------------------------------------------------------------
__global__ void __launch_bounds__(192) k_merge_ln(
    const float* __restrict__ out_y, const float* __restrict__ zg,
    const float* __restrict__ lnw, const float* __restrict__ lnb,
    float* __restrict__ gv) {
  int bl = blockIdx.x;
  int b = bl / L_, lp = bl % L_;
  int h = lp / W_, w = lp % W_;
  int d = threadIdx.x;
  int wave = d >> 6, lane = d & 63;
  float zgv = zg[(size_t)bl * DI_ + d];
  float gw = lnw[d], gb2 = lnb[d];
  __shared__ float wsum[3], wsq[3];
#pragma unroll
  for (int m = 0; m < 3; ++m) {
    int l0;
    if (m == 0) l0 = lp;
    else if (m == 1) l0 = w * H_ + h;
    else l0 = ((w - h + W_) % W_) * H_ + h;
    size_t basef = ((size_t)b * K_ + m) * L_;
    size_t baser = ((size_t)b * K_ + m + 3) * L_;
    float t = out_y[(basef + l0) * DI_ + d] + out_y[(baser + (L_ - 1 - l0)) * DI_ + d];
    float s = t, s2 = t * t;
#pragma unroll
    for (int off = 32; off; off >>= 1) {
      s += __shfl_down(s, off, 64);
      s2 += __shfl_down(s2, off, 64);
    }
    __syncthreads();
    if (lane == 0) { wsum[wave] = s; wsq[wave] = s2; }
    __syncthreads();
    float sum = wsum[0] + wsum[1] + wsum[2];
    float sum2 = wsq[0] + wsq[1] + wsq[2];
    float mu = sum * (1.f / DI_);
    float var = fmaxf(sum2 * (1.f / DI_) - mu * mu, 0.f);
    float g = (t - mu) * rsqrtf(var + 1e-5f) * gw + gb2;
    gv[((size_t)m * (B_ * L_) + bl) * DI_ + d] = g * zgv;
  }
}

// ---------------------------------------------------------------------------
// transpose out_proj_w (96x192) -> wT (192x96)
// ---------------------------------------------------------------------------
__global__ void k_wt(const float* __restrict__ opw, float* __restrict__ wT) {
  int c = blockIdx.x;
  int o = threadIdx.x;
  wT[(size_t)c * DM_ + o] = opw[(size_t)o * DI_ + c];
}

// ---------------------------------------------------------------------------
// K6b: out-proj tiled GEMM.
// ---------------------------------------------------------------------------
constexpr int BM = 64, BK = 32;
__global__ void __launch_bounds__(256) k_outproj(
    const float* __restrict__ gv, const float* __restrict__ wT,
    float* __restrict__ out) {
  __shared__ float As[BM][BK + 1];
  __shared__ float Ws[BK][DM_ + 1];
  int tid = threadIdx.x;
  int tm = tid >> 4, tn = tid & 15;
  int pos0 = blockIdx.x * BM;
  float acc[4][6];
#pragma unroll
  for (int i = 0; i < 4; ++i)
#pragma unroll
    for (int j = 0; j < 6; ++j) acc[i][j] = 0.f;

  for (int k0 = 0; k0 < DI_; k0 += BK) {
#pragma unroll
    for (int it = 0; it < 2; ++it) {
      int i = tid + it * 256;
      int r = i >> 3, c4 = (i & 7) << 2;
      const float4 v = *reinterpret_cast<const float4*>(
          &gv[(size_t)(pos0 + r) * DI_ + k0 + c4]);
      As[r][c4] = v.x; As[r][c4 + 1] = v.y; As[r][c4 + 2] = v.z; As[r][c4 + 3] = v.w;
    }
#pragma unroll
    for (int it = 0; it < 3; ++it) {
      int i = tid + it * 256;
      int r = i / 24, c4 = (i % 24) << 2;
      const float4 v = *reinterpret_cast<const float4*>(
          &wT[(size_t)(k0 + r) * DM_ + c4]);
      Ws[r][c4] = v.x; Ws[r][c4 + 1] = v.y; Ws[r][c4 + 2] = v.z; Ws[r][c4 + 3] = v.w;
    }
    __syncthreads();
#pragma unroll
    for (int kk = 0; kk < BK; ++kk) {
      float a0 = As[tm * 4 + 0][kk], a1 = As[tm * 4 + 1][kk];
      float a2 = As[tm * 4 + 2][kk], a3 = As[tm * 4 + 3][kk];
      float w[6];
#pragma unroll
      for (int j = 0; j < 6; ++j) w[j] = Ws[kk][tn * 6 + j];
#pragma unroll
      for (int j = 0; j < 6; ++j) {
        acc[0][j] += a0 * w[j];
        acc[1][j] += a1 * w[j];
        acc[2][j] += a2 * w[j];
        acc[3][j] += a3 * w[j];
      }
    }
    __syncthreads();
  }
#pragma unroll
  for (int i = 0; i < 4; ++i) {
    size_t ob = (size_t)(pos0 + tm * 4 + i) * DM_ + tn * 6;
#pragma unroll
    for (int j = 0; j < 6; ++j) out[ob + j] = acc[i][j];
  }
}

}  // namespace

extern "C" void kernel_launch(void* const* d_in, const int* in_sizes, int n_in,
                              void* d_out, int out_size, void* d_ws, size_t ws_size,
                              hipStream_t stream) {
  const float* x = (const float*)d_in[0];
  const float* y = (const float*)d_in[1];
  const float* kin = (const float*)d_in[2];
  const float* in_proj_w = (const float*)d_in[3];
  const float* conv_w = (const float*)d_in[4];
  const float* conv_b = (const float*)d_in[5];
  const float* x_proj_w = (const float*)d_in[6];
  const float* dt_w = (const float*)d_in[7];
  const float* dt_b = (const float*)d_in[8];
  const float* A_logs = (const float*)d_in[9];
  const float* Ds = (const float*)d_in[10];
  const float* ln_w = (const float*)d_in[11];
  const float* ln_b = (const float*)d_in[12];
  const float* out_proj_w = (const float*)d_in[13];
  float* out = (float*)d_out;

  float* ws = (float*)d_ws;
  const size_t BLD = (size_t)B_ * L_ * DI_;                 // 884736
  const size_t BKLD = (size_t)B_ * K_ * L_ * DI_;           // 5308416
  const size_t BKLN = (size_t)B_ * K_ * L_ * NS_;           // 442368
  const size_t PSN = (size_t)B_ * K_ * C_ * NS_ * DI_;      // 3538944 = 4*BLD
  // order matters: xv,yv,xc,yc contiguous (aliased by Pbuf), zg after.
  float* xv = ws;             ws += BLD;
  float* yv = ws;             ws += BLD;
  float* xc = ws;             ws += BLD;
  float* yc = ws;             ws += BLD;
  float* zg = ws;             ws += BLD;
  float* xs = ws;             ws += BKLD;
  float* delta = ws;          ws += BKLD;
  float* Bsb = ws;            ws += BKLN;
  float* Csb = ws;            ws += BKLN;
  float* out_y = ws;          ws += BKLD;
  float* SHin = ws;           ws += PSN;
  float* wT = ws;             ws += (size_t)DI_ * DM_;
  float* xpwT = ws;           ws += (size_t)K_ * DI_ * NPAD;
  float* wInT = ws;           ws += (size_t)DM_ * 2 * DI_;
  // aliases onto dead regions:
  float* Pbuf = xv;    // spans xv,yv,xc,yc (4*BLD == PSN), dead after build_xs
  float* gv = delta;   // 3*B*L*DI <= BKLD, delta dead after scan3

  dim3 blk(DI_);
  k_wt<<<DI_, DM_, 0, stream>>>(out_proj_w, wT);
  k_xpwT<<<K_, DI_, 0, stream>>>(x_proj_w, xpwT);
  k_wInT<<<DM_, 2 * DI_, 0, stream>>>(in_proj_w, wInT);
  k_inproj2<<<3 * B_ * L_ / IM, 256, 0, stream>>>(x, y, kin, wInT, xv, yv, zg);
  k_conv<<<B_ * L_, blk, 0, stream>>>(xv, conv_w, conv_b, xc);
  k_conv<<<B_ * L_, blk, 0, stream>>>(yv, conv_w, conv_b, yc);
  k_build_xs<<<B_ * L_, blk, 0, stream>>>(xc, yc, xs);
  k_xdbl2<<<B_ * K_ * L_ / XM, 256, 0, stream>>>(xs, xpwT, dt_w, dt_b, delta, Bsb, Csb);
  k_scan1<<<B_ * K_ * C_, blk, 0, stream>>>(delta, xs, Bsb, A_logs, Pbuf, SHin);
  k_scan2<<<B_ * K_, blk, 0, stream>>>(Pbuf, SHin);
  k_scan3<<<B_ * K_ * C_, blk, 0, stream>>>(delta, xs, Bsb, Csb, A_logs, Ds, SHin, out_y);
  k_merge_ln<<<B_ * L_, blk, 0, stream>>>(out_y, zg, ln_w, ln_b, gv);
  k_outproj<<<3 * B_ * L_ / BM, 256, 0, stream>>>(gv, wT, out);
}

// Round 6
// 217.959 us; speedup vs baseline: 12.1465x; 1.1165x over previous
//
#include <hip/hip_runtime.h>
#include <hip/hip_bf16.h>

namespace {

constexpr int B_ = 2, H_ = 48, W_ = 48, DM_ = 96, DI_ = 192, NS_ = 16, RK_ = 6, K_ = 6;
constexpr int L_ = H_ * W_;
constexpr int C_ = 96;            // chunks per (b,k) stream
constexpr int LC_ = L_ / C_;      // 24 steps per chunk
constexpr int NPROJ = RK_ + 2 * NS_;  // 38
constexpr int NPAD = 48;              // padded N for the xdbl GEMM

__device__ __forceinline__ float sigmoidf_(float x) { return 1.f / (1.f + __expf(-x)); }

// ---------------------------------------------------------------------------
// transpose in_proj_w (384x96) -> wInT (96x384)
// ---------------------------------------------------------------------------
__global__ void k_wInT(const float* __restrict__ Wp, float* __restrict__ wInT) {
  int c = blockIdx.x;        // 0..95
  int o = threadIdx.x;       // 0..383
  wInT[(size_t)c * (2 * DI_) + o] = Wp[(size_t)o * DM_ + c];
}

// ---------------------------------------------------------------------------
// K1: in_proj as tiled GEMM.  Streams s=0(x->xv), 1(y->yv), 2(k->silu->zg).
// ---------------------------------------------------------------------------
constexpr int IM = 64, IBK = 32;
__global__ void __launch_bounds__(256) k_inproj2(
    const float* __restrict__ x, const float* __restrict__ y,
    const float* __restrict__ kin, const float* __restrict__ wInT,
    float* __restrict__ xv, float* __restrict__ yv, float* __restrict__ zg) {
  __shared__ float As[IM][IBK + 1];
  __shared__ float Ws[IBK][DI_ + 1];
  int tid = threadIdx.x;
  constexpr int BPS = (B_ * L_) / IM;   // 72 blocks per stream
  int s = blockIdx.x / BPS;
  int row0 = (blockIdx.x % BPS) * IM;
  const float* src = (s == 0) ? x : (s == 1) ? y : kin;
  float* dst = (s == 0) ? xv : (s == 1) ? yv : zg;
  int nbase = (s == 2) ? DI_ : 0;
  int tm = tid >> 4, tn = tid & 15;     // 16 x 16
  float acc[4][12];
#pragma unroll
  for (int i = 0; i < 4; ++i)
#pragma unroll
    for (int j = 0; j < 12; ++j) acc[i][j] = 0.f;

  for (int k0 = 0; k0 < DM_; k0 += IBK) {
#pragma unroll
    for (int it = 0; it < 2; ++it) {
      int i = tid + it * 256;
      int r = i >> 3, c4 = (i & 7) << 2;
      const float4 v = *reinterpret_cast<const float4*>(
          &src[(size_t)(row0 + r) * DM_ + k0 + c4]);
      As[r][c4] = v.x; As[r][c4 + 1] = v.y; As[r][c4 + 2] = v.z; As[r][c4 + 3] = v.w;
    }
#pragma unroll
    for (int it = 0; it < 6; ++it) {
      int i = tid + it * 256;
      int r = i / 48, c4 = (i % 48) << 2;
      const float4 v = *reinterpret_cast<const float4*>(
          &wInT[(size_t)(k0 + r) * (2 * DI_) + nbase + c4]);
      Ws[r][c4] = v.x; Ws[r][c4 + 1] = v.y; Ws[r][c4 + 2] = v.z; Ws[r][c4 + 3] = v.w;
    }
    __syncthreads();
#pragma unroll
    for (int kk = 0; kk < IBK; ++kk) {
      float a[4];
#pragma unroll
      for (int i = 0; i < 4; ++i) a[i] = As[tm * 4 + i][kk];
      float w[12];
#pragma unroll
      for (int j = 0; j < 12; ++j) w[j] = Ws[kk][tn * 12 + j];
#pragma unroll
      for (int i = 0; i < 4; ++i)
#pragma unroll
        for (int j = 0; j < 12; ++j) acc[i][j] += a[i] * w[j];
    }
    __syncthreads();
  }
#pragma unroll
  for (int i = 0; i < 4; ++i) {
    size_t ob = (size_t)(row0 + tm * 4 + i) * DI_ + tn * 12;
#pragma unroll
    for (int j = 0; j < 12; ++j) {
      float v = acc[i][j];
      if (s == 2) v = v * sigmoidf_(v);
      dst[ob + j] = v;
    }
  }
}

// ---------------------------------------------------------------------------
// K2+K3 fused: depthwise 3x3 conv + SiLU on xv AND yv, scatter directly into
// the 6 direction streams (diag gather becomes scatter).  grid = B*L, 192 thr.
// ---------------------------------------------------------------------------
__global__ void __launch_bounds__(192) k_conv_xs(
    const float* __restrict__ xv, const float* __restrict__ yv,
    const float* __restrict__ cw, const float* __restrict__ cb,
    float* __restrict__ xs) {
  int bl = blockIdx.x;
  int d = threadIdx.x;
  int b = bl / L_, l = bl % L_;
  int h = l / W_, w = l % W_;
  float bias = cb[d];
  float ax = bias, ay = bias;
  const float* wp = cw + d * 9;
#pragma unroll
  for (int kh = 0; kh < 3; ++kh) {
    int hh = h + kh - 1;
    if (hh < 0 || hh >= H_) continue;
#pragma unroll
    for (int kw = 0; kw < 3; ++kw) {
      int ww = w + kw - 1;
      if (ww < 0 || ww >= W_) continue;
      float wk = wp[kh * 3 + kw];
      size_t idx = ((size_t)b * L_ + hh * W_ + ww) * DI_ + d;
      ax += xv[idx] * wk;
      ay += yv[idx] * wk;
    }
  }
  ax = ax * sigmoidf_(ax);
  ay = ay * sigmoidf_(ay);
  size_t base = (size_t)b * K_ * L_;
  int lv = w * H_ + h;                     // column-major position
  int w2 = (w - h + W_) % W_;              // diag scatter destination column
  int lv2 = w2 * H_ + h;
  xs[(base + (size_t)0 * L_ + l) * DI_ + d] = ax;
  xs[(base + (size_t)3 * L_ + (L_ - 1 - l)) * DI_ + d] = ax;
  xs[(base + (size_t)1 * L_ + lv) * DI_ + d] = ay;
  xs[(base + (size_t)4 * L_ + (L_ - 1 - lv)) * DI_ + d] = ay;
  xs[(base + (size_t)2 * L_ + lv2) * DI_ + d] = ay;
  xs[(base + (size_t)5 * L_ + (L_ - 1 - lv2)) * DI_ + d] = ay;
}

// ---------------------------------------------------------------------------
// transpose+pad x_proj_w: xpwT[k][dd][c] = xpw[k][c][dd]  (c<38, else 0)
// ---------------------------------------------------------------------------
__global__ void k_xpwT(const float* __restrict__ xpw, float* __restrict__ xpwT) {
  int k = blockIdx.x;
  int dd = threadIdx.x;
  float* dst = xpwT + ((size_t)k * DI_ + dd) * NPAD;
  for (int c = 0; c < NPAD; ++c)
    dst[c] = (c < NPROJ) ? xpw[((size_t)k * NPROJ + c) * DI_ + dd] : 0.f;
}

// ---------------------------------------------------------------------------
// K4a: x_dbl GEMM.  M tiles of 32, N = 48(pad of 38), K = 192.
// Direct accumulator writes -> dts / Bs / Cs.  grid = 864, block 256.
// ---------------------------------------------------------------------------
constexpr int XM = 32, XBK = 32;
__global__ void __launch_bounds__(256) k_xdbl3(
    const float* __restrict__ xs, const float* __restrict__ xpwT,
    float* __restrict__ dts, float* __restrict__ Bsb, float* __restrict__ Csb) {
  __shared__ float As[XM][XBK + 1];
  __shared__ float Ws[XBK][NPAD];
  int tid = threadIdx.x;
  int row0 = blockIdx.x * XM;
  int k = (row0 / L_) % K_;
  int tm = tid >> 4, tn = tid & 15;    // 16 x 16 -> rows 2/thread, cols 3/thread
  float acc[2][3];
#pragma unroll
  for (int i = 0; i < 2; ++i)
#pragma unroll
    for (int j = 0; j < 3; ++j) acc[i][j] = 0.f;

  for (int k0 = 0; k0 < DI_; k0 += XBK) {
    {  // A tile: 32x32 = 256 float4, 1/thread
      int r = tid >> 3, c4 = (tid & 7) << 2;
      const float4 v = *reinterpret_cast<const float4*>(
          &xs[(size_t)(row0 + r) * DI_ + k0 + c4]);
      As[r][c4] = v.x; As[r][c4 + 1] = v.y; As[r][c4 + 2] = v.z; As[r][c4 + 3] = v.w;
    }
#pragma unroll
    for (int it = 0; it < 2; ++it) {   // W tile: 32x48 = 384 float4
      int i = tid + it * 256;
      if (i < 384) {
        int r = i / 12, c4 = (i % 12) << 2;
        const float4 v = *reinterpret_cast<const float4*>(
            &xpwT[((size_t)k * DI_ + k0 + r) * NPAD + c4]);
        Ws[r][c4] = v.x; Ws[r][c4 + 1] = v.y; Ws[r][c4 + 2] = v.z; Ws[r][c4 + 3] = v.w;
      }
    }
    __syncthreads();
#pragma unroll
    for (int kk = 0; kk < XBK; ++kk) {
      float a0 = As[tm * 2 + 0][kk], a1 = As[tm * 2 + 1][kk];
      float w0 = Ws[kk][tn * 3 + 0], w1 = Ws[kk][tn * 3 + 1], w2 = Ws[kk][tn * 3 + 2];
      acc[0][0] += a0 * w0; acc[0][1] += a0 * w1; acc[0][2] += a0 * w2;
      acc[1][0] += a1 * w0; acc[1][1] += a1 * w1; acc[1][2] += a1 * w2;
    }
    __syncthreads();
  }
#pragma unroll
  for (int i = 0; i < 2; ++i) {
    int row = row0 + tm * 2 + i;
#pragma unroll
    for (int j = 0; j < 3; ++j) {
      int cc = tn * 3 + j;
      float v = acc[i][j];
      if (cc < RK_) dts[(size_t)row * RK_ + cc] = v;
      else if (cc < RK_ + NS_) Bsb[(size_t)row * NS_ + (cc - RK_)] = v;
      else if (cc < NPROJ) Csb[(size_t)row * NS_ + (cc - RK_ - NS_)] = v;
    }
  }
}

// ---------------------------------------------------------------------------
// K4b: delta = softplus(dtw @ dts + dtb).  8 rows/block, 192 threads.
// grid = B*K*L/8 = 3456.
// ---------------------------------------------------------------------------
constexpr int DR_ = 8;
__global__ void __launch_bounds__(192) k_delta(
    const float* __restrict__ dts, const float* __restrict__ dtw,
    const float* __restrict__ dtb, float* __restrict__ delta) {
  int row0 = blockIdx.x * DR_;
  int k = (row0 / L_) % K_;
  int d = threadIdx.x;
  __shared__ float sdtw[DI_][7];       // stride 7: gcd(7,32)=1 -> 2-way max
  __shared__ float sdts[DR_][RK_];
  for (int i = d; i < DI_ * RK_; i += 192) sdtw[i / RK_][i % RK_] = dtw[(size_t)k * DI_ * RK_ + i];
  if (d < DR_ * RK_) ((float*)sdts)[d] = dts[(size_t)row0 * RK_ + d];
  __syncthreads();
  float bias = dtb[k * DI_ + d];
  const float* wrow = sdtw[d];
#pragma unroll
  for (int i = 0; i < DR_; ++i) {
    float s = bias;
#pragma unroll
    for (int r = 0; r < RK_; ++r) s += sdts[i][r] * wrow[r];
    float dl = (s > 20.f) ? s : __logf(1.f + __expf(s));
    delta[(size_t)(row0 + i) * DI_ + d] = dl;
  }
}

// ---------------------------------------------------------------------------
// K5a: chunked scan pass 1.  P via exp(A*sum_dl); S via fast-exp recurrence.
// ---------------------------------------------------------------------------
__global__ void __launch_bounds__(192) k_scan1(
    const float* __restrict__ delta, const float* __restrict__ xs,
    const float* __restrict__ Bsb, const float* __restrict__ A_logs,
    float* __restrict__ Pbuf, float* __restrict__ SHin) {
  int blk = blockIdx.x;            // bk*C_ + c
  int bk = blk / C_, c = blk % C_;
  int k = bk % K_;
  int d = threadIdx.x;
  float A[NS_];
#pragma unroll
  for (int n = 0; n < NS_; ++n) A[n] = -__expf(A_logs[((size_t)k * DI_ + d) * NS_ + n]);
  float S[NS_];
#pragma unroll
  for (int n = 0; n < NS_; ++n) S[n] = 0.f;
  float sum_dl = 0.f;
  size_t base = (size_t)bk * L_ + (size_t)c * LC_;
  for (int l = 0; l < LC_; ++l) {
    float dl = delta[(base + l) * DI_ + d];
    float u = xs[(base + l) * DI_ + d];
    float du = dl * u;
    sum_dl += dl;
    const float* Bp = Bsb + (base + l) * NS_;
#pragma unroll
    for (int n = 0; n < NS_; ++n) {
      float e = __expf(dl * A[n]);
      S[n] = e * S[n] + du * Bp[n];
    }
  }
  size_t ob = (size_t)blk * NS_ * DI_ + d;
#pragma unroll
  for (int n = 0; n < NS_; ++n) {
    Pbuf[ob + (size_t)n * DI_] = __expf(A[n] * sum_dl);
    SHin[ob + (size_t)n * DI_] = S[n];
  }
}

// ---------------------------------------------------------------------------
// K5b: chunk-level scan; SHin holds S on entry, h_in on exit (in-place).
// ---------------------------------------------------------------------------
__global__ void __launch_bounds__(192) k_scan2(
    const float* __restrict__ Pbuf, float* __restrict__ SHin) {
  int bk = blockIdx.x;
  int d = threadIdx.x;
  float h[NS_];
#pragma unroll
  for (int n = 0; n < NS_; ++n) h[n] = 0.f;
  for (int c = 0; c < C_; ++c) {
    size_t base = ((size_t)(bk * C_ + c) * NS_) * DI_ + d;
#pragma unroll
    for (int n = 0; n < NS_; ++n) {
      size_t i = base + (size_t)n * DI_;
      float s = SHin[i];
      float p = Pbuf[i];
      SHin[i] = h[n];
      h[n] = p * h[n] + s;
    }
  }
}

// ---------------------------------------------------------------------------
// K5c: chunked scan pass 3 — recompute from h_in, emit out_y.
// ---------------------------------------------------------------------------
__global__ void __launch_bounds__(192) k_scan3(
    const float* __restrict__ delta, const float* __restrict__ xs,
    const float* __restrict__ Bsb, const float* __restrict__ Csb,
    const float* __restrict__ A_logs, const float* __restrict__ Ds,
    const float* __restrict__ SHin, float* __restrict__ out_y) {
  int blk = blockIdx.x;            // bk*C_ + c
  int bk = blk / C_, c = blk % C_;
  int k = bk % K_;
  int d = threadIdx.x;
  float A[NS_];
#pragma unroll
  for (int n = 0; n < NS_; ++n) A[n] = -__expf(A_logs[((size_t)k * DI_ + d) * NS_ + n]);
  float Dk = Ds[k * DI_ + d];
  float h[NS_];
  size_t hb = (size_t)blk * NS_ * DI_ + d;
#pragma unroll
  for (int n = 0; n < NS_; ++n) h[n] = SHin[hb + (size_t)n * DI_];
  size_t base = (size_t)bk * L_ + (size_t)c * LC_;
  for (int l = 0; l < LC_; ++l) {
    float dl = delta[(base + l) * DI_ + d];
    float u = xs[(base + l) * DI_ + d];
    float du = dl * u;
    const float* Bp = Bsb + (base + l) * NS_;
    const float* Cp = Csb + (base + l) * NS_;
    float yacc = 0.f;
#pragma unroll
    for (int n = 0; n < NS_; ++n) {
      h[n] = __expf(dl * A[n]) * h[n] + du * Bp[n];
      yacc += h[n] * Cp[n];
    }
    out_y[(base + l) * DI_ + d] = yacc + Dk * u;
  }
}

// ---------------------------------------------------------------------------
// K6a: merge directions + LayerNorm + gate -> gv.
// ---------------------------------------------------------------------------
__global__ void __launch_bounds__(192) k_merge_ln(
    const float* __restrict__ out_y, const float* __restrict__ zg,
    const float* __restrict__ lnw, const float* __restrict__ lnb,
    float* __restrict__ gv) {
  int bl = blockIdx.x;
  int b = bl / L_, lp = bl % L_;
  int h = lp / W_, w = lp % W_;
  int d = threadIdx.x;
  int wave = d >> 6, lane = d & 63;
  float zgv = zg[(size_t)bl * DI_ + d];
  float gw = lnw[d], gb2 = lnb[d];
  __shared__ float wsum[3], wsq[3];
#pragma unroll
  for (int m = 0; m < 3; ++m) {
    int l0;
    if (m == 0) l0 = lp;
    else if (m == 1) l0 = w * H_ + h;
    else l0 = ((w - h + W_) % W_) * H_ + h;
    size_t basef = ((size_t)b * K_ + m) * L_;
    size_t baser = ((size_t)b * K_ + m + 3) * L_;
    float t = out_y[(basef + l0) * DI_ + d] + out_y[(baser + (L_ - 1 - l0)) * DI_ + d];
    float s = t, s2 = t * t;
#pragma unroll
    for (int off = 32; off; off >>= 1) {
      s += __shfl_down(s, off, 64);
      s2 += __shfl_down(s2, off, 64);
    }
    __syncthreads();
    if (lane == 0) { wsum[wave] = s; wsq[wave] = s2; }
    __syncthreads();
    float sum = wsum[0] + wsum[1] + wsum[2];
    float sum2 = wsq[0] + wsq[1] + wsq[2];
    float mu = sum * (1.f / DI_);
    float var = fmaxf(sum2 * (1.f / DI_) - mu * mu, 0.f);
    float g = (t - mu) * rsqrtf(var + 1e-5f) * gw + gb2;
    gv[((size_t)m * (B_ * L_) + bl) * DI_ + d] = g * zgv;
  }
}

// ---------------------------------------------------------------------------
// transpose out_proj_w (96x192) -> wT (192x96)
// ---------------------------------------------------------------------------
__global__ void k_wt(const float* __restrict__ opw, float* __restrict__ wT) {
  int c = blockIdx.x;
  int o = threadIdx.x;
  wT[(size_t)c * DM_ + o] = opw[(size_t)o * DI_ + c];
}

// ---------------------------------------------------------------------------
// K6b: out-proj tiled GEMM.
// ---------------------------------------------------------------------------
constexpr int BM = 64, BK = 32;
__global__ void __launch_bounds__(256) k_outproj(
    const float* __restrict__ gv, const float* __restrict__ wT,
    float* __restrict__ out) {
  __shared__ float As[BM][BK + 1];
  __shared__ float Ws[BK][DM_ + 1];
  int tid = threadIdx.x;
  int tm = tid >> 4, tn = tid & 15;
  int pos0 = blockIdx.x * BM;
  float acc[4][6];
#pragma unroll
  for (int i = 0; i < 4; ++i)
#pragma unroll
    for (int j = 0; j < 6; ++j) acc[i][j] = 0.f;

  for (int k0 = 0; k0 < DI_; k0 += BK) {
#pragma unroll
    for (int it = 0; it < 2; ++it) {
      int i = tid + it * 256;
      int r = i >> 3, c4 = (i & 7) << 2;
      const float4 v = *reinterpret_cast<const float4*>(
          &gv[(size_t)(pos0 + r) * DI_ + k0 + c4]);
      As[r][c4] = v.x; As[r][c4 + 1] = v.y; As[r][c4 + 2] = v.z; As[r][c4 + 3] = v.w;
    }
#pragma unroll
    for (int it = 0; it < 3; ++it) {
      int i = tid + it * 256;
      int r = i / 24, c4 = (i % 24) << 2;
      const float4 v = *reinterpret_cast<const float4*>(
          &wT[(size_t)(k0 + r) * DM_ + c4]);
      Ws[r][c4] = v.x; Ws[r][c4 + 1] = v.y; Ws[r][c4 + 2] = v.z; Ws[r][c4 + 3] = v.w;
    }
    __syncthreads();
#pragma unroll
    for (int kk = 0; kk < BK; ++kk) {
      float a0 = As[tm * 4 + 0][kk], a1 = As[tm * 4 + 1][kk];
      float a2 = As[tm * 4 + 2][kk], a3 = As[tm * 4 + 3][kk];
      float w[6];
#pragma unroll
      for (int j = 0; j < 6; ++j) w[j] = Ws[kk][tn * 6 + j];
#pragma unroll
      for (int j = 0; j < 6; ++j) {
        acc[0][j] += a0 * w[j];
        acc[1][j] += a1 * w[j];
        acc[2][j] += a2 * w[j];
        acc[3][j] += a3 * w[j];
      }
    }
    __syncthreads();
  }
#pragma unroll
  for (int i = 0; i < 4; ++i) {
    size_t ob = (size_t)(pos0 + tm * 4 + i) * DM_ + tn * 6;
#pragma unroll
    for (int j = 0; j < 6; ++j) out[ob + j] = acc[i][j];
  }
}

}  // namespace

extern "C" void kernel_launch(void* const* d_in, const int* in_sizes, int n_in,
                              void* d_out, int out_size, void* d_ws, size_t ws_size,
                              hipStream_t stream) {
  const float* x = (const float*)d_in[0];
  const float* y = (const float*)d_in[1];
  const float* kin = (const float*)d_in[2];
  const float* in_proj_w = (const float*)d_in[3];
  const float* conv_w = (const float*)d_in[4];
  const float* conv_b = (const float*)d_in[5];
  const float* x_proj_w = (const float*)d_in[6];
  const float* dt_w = (const float*)d_in[7];
  const float* dt_b = (const float*)d_in[8];
  const float* A_logs = (const float*)d_in[9];
  const float* Ds = (const float*)d_in[10];
  const float* ln_w = (const float*)d_in[11];
  const float* ln_b = (const float*)d_in[12];
  const float* out_proj_w = (const float*)d_in[13];
  float* out = (float*)d_out;

  float* ws = (float*)d_ws;
  const size_t BLD = (size_t)B_ * L_ * DI_;                 // 884736
  const size_t BKLD = (size_t)B_ * K_ * L_ * DI_;           // 5308416
  const size_t BKLN = (size_t)B_ * K_ * L_ * NS_;           // 442368
  const size_t PSN = (size_t)B_ * K_ * C_ * NS_ * DI_;      // 3538944 = 4*BLD
  // xv,yv + 2*BLD pad form the contiguous Pbuf alias region.
  float* xv = ws;             ws += BLD;
  float* yv = ws;             ws += BLD;
  /* pext */                  ws += 2 * BLD;
  float* zg = ws;             ws += BLD;
  float* xs = ws;             ws += BKLD;
  float* delta = ws;          ws += BKLD;
  float* Bsb = ws;            ws += BKLN;
  float* Csb = ws;            ws += BKLN;
  float* out_y = ws;          ws += BKLD;
  float* SHin = ws;           ws += PSN;
  float* wT = ws;             ws += (size_t)DI_ * DM_;
  float* xpwT = ws;           ws += (size_t)K_ * DI_ * NPAD;
  float* wInT = ws;           ws += (size_t)DM_ * 2 * DI_;
  float* dts = ws;            ws += (size_t)B_ * K_ * L_ * RK_;
  // aliases onto dead regions:
  float* Pbuf = xv;    // spans xv,yv,pext (4*BLD == PSN), dead after conv_xs
  float* gv = delta;   // 3*B*L*DI <= BKLD, delta dead after scan3

  dim3 blk(DI_);
  k_wt<<<DI_, DM_, 0, stream>>>(out_proj_w, wT);
  k_xpwT<<<K_, DI_, 0, stream>>>(x_proj_w, xpwT);
  k_wInT<<<DM_, 2 * DI_, 0, stream>>>(in_proj_w, wInT);
  k_inproj2<<<3 * B_ * L_ / IM, 256, 0, stream>>>(x, y, kin, wInT, xv, yv, zg);
  k_conv_xs<<<B_ * L_, blk, 0, stream>>>(xv, yv, conv_w, conv_b, xs);
  k_xdbl3<<<B_ * K_ * L_ / XM, 256, 0, stream>>>(xs, xpwT, dts, Bsb, Csb);
  k_delta<<<B_ * K_ * L_ / DR_, blk, 0, stream>>>(dts, dt_w, dt_b, delta);
  k_scan1<<<B_ * K_ * C_, blk, 0, stream>>>(delta, xs, Bsb, A_logs, Pbuf, SHin);
  k_scan2<<<B_ * K_, blk, 0, stream>>>(Pbuf, SHin);
  k_scan3<<<B_ * K_ * C_, blk, 0, stream>>>(delta, xs, Bsb, Csb, A_logs, Ds, SHin, out_y);
  k_merge_ln<<<B_ * L_, blk, 0, stream>>>(out_y, zg, ln_w, ln_b, gv);
  k_outproj<<<3 * B_ * L_ / BM, 256, 0, stream>>>(gv, wT, out);
}

// Round 7
// 176.994 us; speedup vs baseline: 14.9578x; 1.2315x over previous
//
#include <hip/hip_runtime.h>
#include <hip/hip_bf16.h>

namespace {

constexpr int B_ = 2, H_ = 48, W_ = 48, DM_ = 96, DI_ = 192, NS_ = 16, RK_ = 6, K_ = 6;
constexpr int L_ = H_ * W_;
constexpr int C_ = 96;            // chunks per (b,k) stream
constexpr int LC_ = L_ / C_;      // 24 steps per chunk
constexpr int NPROJ = RK_ + 2 * NS_;  // 38
constexpr int NPAD = 48;              // padded N for the xdbl GEMM

__device__ __forceinline__ float sigmoidf_(float x) { return 1.f / (1.f + __expf(-x)); }

// ---------------------------------------------------------------------------
// K0: all weight prep in one launch.  grid = 96 + 6 + 192 = 294, block 384.
//  blocks [0,96):    wInT[c][o]   = in_proj_w[o][c]
//  blocks [96,102):  xpwT[k][dd][c] = x_proj_w[k][c][dd]  (pad c to 48)
//  blocks [102,294): wT[c][o]     = out_proj_w[o][c]
// ---------------------------------------------------------------------------
__global__ void k_prep(const float* __restrict__ Wp, const float* __restrict__ xpw,
                       const float* __restrict__ opw, float* __restrict__ wInT,
                       float* __restrict__ xpwT, float* __restrict__ wT) {
  int blk = blockIdx.x;
  int tid = threadIdx.x;
  if (blk < DM_) {
    wInT[(size_t)blk * (2 * DI_) + tid] = Wp[(size_t)tid * DM_ + blk];
  } else if (blk < DM_ + K_) {
    int k = blk - DM_;
    if (tid < DI_) {
      float* dst = xpwT + ((size_t)k * DI_ + tid) * NPAD;
      for (int c = 0; c < NPAD; ++c)
        dst[c] = (c < NPROJ) ? xpw[((size_t)k * NPROJ + c) * DI_ + tid] : 0.f;
    }
  } else {
    int c = blk - DM_ - K_;
    if (tid < DM_)
      wT[(size_t)c * DM_ + tid] = opw[(size_t)tid * DI_ + c];
  }
}

// ---------------------------------------------------------------------------
// K1: in_proj as tiled GEMM.  Streams s=0(x->xv), 1(y->yv), 2(k->silu->zg).
// ---------------------------------------------------------------------------
constexpr int IM = 64, IBK = 32;
__global__ void __launch_bounds__(256) k_inproj2(
    const float* __restrict__ x, const float* __restrict__ y,
    const float* __restrict__ kin, const float* __restrict__ wInT,
    float* __restrict__ xv, float* __restrict__ yv, float* __restrict__ zg) {
  __shared__ float As[IM][IBK + 1];
  __shared__ float Ws[IBK][DI_ + 1];
  int tid = threadIdx.x;
  constexpr int BPS = (B_ * L_) / IM;   // 72 blocks per stream
  int s = blockIdx.x / BPS;
  int row0 = (blockIdx.x % BPS) * IM;
  const float* src = (s == 0) ? x : (s == 1) ? y : kin;
  float* dst = (s == 0) ? xv : (s == 1) ? yv : zg;
  int nbase = (s == 2) ? DI_ : 0;
  int tm = tid >> 4, tn = tid & 15;     // 16 x 16
  float acc[4][12];
#pragma unroll
  for (int i = 0; i < 4; ++i)
#pragma unroll
    for (int j = 0; j < 12; ++j) acc[i][j] = 0.f;

  for (int k0 = 0; k0 < DM_; k0 += IBK) {
#pragma unroll
    for (int it = 0; it < 2; ++it) {
      int i = tid + it * 256;
      int r = i >> 3, c4 = (i & 7) << 2;
      const float4 v = *reinterpret_cast<const float4*>(
          &src[(size_t)(row0 + r) * DM_ + k0 + c4]);
      As[r][c4] = v.x; As[r][c4 + 1] = v.y; As[r][c4 + 2] = v.z; As[r][c4 + 3] = v.w;
    }
#pragma unroll
    for (int it = 0; it < 6; ++it) {
      int i = tid + it * 256;
      int r = i / 48, c4 = (i % 48) << 2;
      const float4 v = *reinterpret_cast<const float4*>(
          &wInT[(size_t)(k0 + r) * (2 * DI_) + nbase + c4]);
      Ws[r][c4] = v.x; Ws[r][c4 + 1] = v.y; Ws[r][c4 + 2] = v.z; Ws[r][c4 + 3] = v.w;
    }
    __syncthreads();
#pragma unroll
    for (int kk = 0; kk < IBK; ++kk) {
      float a[4];
#pragma unroll
      for (int i = 0; i < 4; ++i) a[i] = As[tm * 4 + i][kk];
      float w[12];
#pragma unroll
      for (int j = 0; j < 12; ++j) w[j] = Ws[kk][tn * 12 + j];
#pragma unroll
      for (int i = 0; i < 4; ++i)
#pragma unroll
        for (int j = 0; j < 12; ++j) acc[i][j] += a[i] * w[j];
    }
    __syncthreads();
  }
#pragma unroll
  for (int i = 0; i < 4; ++i) {
    size_t ob = (size_t)(row0 + tm * 4 + i) * DI_ + tn * 12;
#pragma unroll
    for (int j = 0; j < 12; ++j) {
      float v = acc[i][j];
      if (s == 2) v = v * sigmoidf_(v);
      dst[ob + j] = v;
    }
  }
}

// ---------------------------------------------------------------------------
// K2+K3 fused: depthwise 3x3 conv + SiLU on xv AND yv, scatter into 6 streams.
// ---------------------------------------------------------------------------
__global__ void __launch_bounds__(192) k_conv_xs(
    const float* __restrict__ xv, const float* __restrict__ yv,
    const float* __restrict__ cw, const float* __restrict__ cb,
    float* __restrict__ xs) {
  int bl = blockIdx.x;
  int d = threadIdx.x;
  int b = bl / L_, l = bl % L_;
  int h = l / W_, w = l % W_;
  float bias = cb[d];
  float ax = bias, ay = bias;
  const float* wp = cw + d * 9;
#pragma unroll
  for (int kh = 0; kh < 3; ++kh) {
    int hh = h + kh - 1;
    if (hh < 0 || hh >= H_) continue;
#pragma unroll
    for (int kw = 0; kw < 3; ++kw) {
      int ww = w + kw - 1;
      if (ww < 0 || ww >= W_) continue;
      float wk = wp[kh * 3 + kw];
      size_t idx = ((size_t)b * L_ + hh * W_ + ww) * DI_ + d;
      ax += xv[idx] * wk;
      ay += yv[idx] * wk;
    }
  }
  ax = ax * sigmoidf_(ax);
  ay = ay * sigmoidf_(ay);
  size_t base = (size_t)b * K_ * L_;
  int lv = w * H_ + h;
  int w2 = (w - h + W_) % W_;
  int lv2 = w2 * H_ + h;
  xs[(base + (size_t)0 * L_ + l) * DI_ + d] = ax;
  xs[(base + (size_t)3 * L_ + (L_ - 1 - l)) * DI_ + d] = ax;
  xs[(base + (size_t)1 * L_ + lv) * DI_ + d] = ay;
  xs[(base + (size_t)4 * L_ + (L_ - 1 - lv)) * DI_ + d] = ay;
  xs[(base + (size_t)2 * L_ + lv2) * DI_ + d] = ay;
  xs[(base + (size_t)5 * L_ + (L_ - 1 - lv2)) * DI_ + d] = ay;
}

// ---------------------------------------------------------------------------
// K4a: x_dbl GEMM.  M tiles of 32, N = 48(pad of 38), K = 192.
// ---------------------------------------------------------------------------
constexpr int XM = 32, XBK = 32;
__global__ void __launch_bounds__(256) k_xdbl3(
    const float* __restrict__ xs, const float* __restrict__ xpwT,
    float* __restrict__ dts, float* __restrict__ Bsb, float* __restrict__ Csb) {
  __shared__ float As[XM][XBK + 1];
  __shared__ float Ws[XBK][NPAD];
  int tid = threadIdx.x;
  int row0 = blockIdx.x * XM;
  int k = (row0 / L_) % K_;
  int tm = tid >> 4, tn = tid & 15;
  float acc[2][3];
#pragma unroll
  for (int i = 0; i < 2; ++i)
#pragma unroll
    for (int j = 0; j < 3; ++j) acc[i][j] = 0.f;

  for (int k0 = 0; k0 < DI_; k0 += XBK) {
    {
      int r = tid >> 3, c4 = (tid & 7) << 2;
      const float4 v = *reinterpret_cast<const float4*>(
          &xs[(size_t)(row0 + r) * DI_ + k0 + c4]);
      As[r][c4] = v.x; As[r][c4 + 1] = v.y; As[r][c4 + 2] = v.z; As[r][c4 + 3] = v.w;
    }
#pragma unroll
    for (int it = 0; it < 2; ++it) {
      int i = tid + it * 256;
      if (i < 384) {
        int r = i / 12, c4 = (i % 12) << 2;
        const float4 v = *reinterpret_cast<const float4*>(
            &xpwT[((size_t)k * DI_ + k0 + r) * NPAD + c4]);
        Ws[r][c4] = v.x; Ws[r][c4 + 1] = v.y; Ws[r][c4 + 2] = v.z; Ws[r][c4 + 3] = v.w;
      }
    }
    __syncthreads();
#pragma unroll
    for (int kk = 0; kk < XBK; ++kk) {
      float a0 = As[tm * 2 + 0][kk], a1 = As[tm * 2 + 1][kk];
      float w0 = Ws[kk][tn * 3 + 0], w1 = Ws[kk][tn * 3 + 1], w2 = Ws[kk][tn * 3 + 2];
      acc[0][0] += a0 * w0; acc[0][1] += a0 * w1; acc[0][2] += a0 * w2;
      acc[1][0] += a1 * w0; acc[1][1] += a1 * w1; acc[1][2] += a1 * w2;
    }
    __syncthreads();
  }
#pragma unroll
  for (int i = 0; i < 2; ++i) {
    int row = row0 + tm * 2 + i;
#pragma unroll
    for (int j = 0; j < 3; ++j) {
      int cc = tn * 3 + j;
      float v = acc[i][j];
      if (cc < RK_) dts[(size_t)row * RK_ + cc] = v;
      else if (cc < RK_ + NS_) Bsb[(size_t)row * NS_ + (cc - RK_)] = v;
      else if (cc < NPROJ) Csb[(size_t)row * NS_ + (cc - RK_ - NS_)] = v;
    }
  }
}

// ---------------------------------------------------------------------------
// K4b: delta = softplus(dtw @ dts + dtb).
// ---------------------------------------------------------------------------
constexpr int DR_ = 8;
__global__ void __launch_bounds__(192) k_delta(
    const float* __restrict__ dts, const float* __restrict__ dtw,
    const float* __restrict__ dtb, float* __restrict__ delta) {
  int row0 = blockIdx.x * DR_;
  int k = (row0 / L_) % K_;
  int d = threadIdx.x;
  __shared__ float sdtw[DI_][7];
  __shared__ float sdts[DR_][RK_];
  for (int i = d; i < DI_ * RK_; i += 192) sdtw[i / RK_][i % RK_] = dtw[(size_t)k * DI_ * RK_ + i];
  if (d < DR_ * RK_) ((float*)sdts)[d] = dts[(size_t)row0 * RK_ + d];
  __syncthreads();
  float bias = dtb[k * DI_ + d];
  const float* wrow = sdtw[d];
#pragma unroll
  for (int i = 0; i < DR_; ++i) {
    float s = bias;
#pragma unroll
    for (int r = 0; r < RK_; ++r) s += sdts[i][r] * wrow[r];
    float dl = (s > 20.f) ? s : __logf(1.f + __expf(s));
    delta[(size_t)(row0 + i) * DI_ + d] = dl;
  }
}

// ---------------------------------------------------------------------------
// K5a: chunked scan pass 1.  P via exp(A*sum_dl); S via fast-exp recurrence.
// ---------------------------------------------------------------------------
__global__ void __launch_bounds__(192) k_scan1(
    const float* __restrict__ delta, const float* __restrict__ xs,
    const float* __restrict__ Bsb, const float* __restrict__ A_logs,
    float* __restrict__ Pbuf, float* __restrict__ SHin) {
  int blk = blockIdx.x;            // bk*C_ + c
  int bk = blk / C_, c = blk % C_;
  int k = bk % K_;
  int d = threadIdx.x;
  float A[NS_];
#pragma unroll
  for (int n = 0; n < NS_; ++n) A[n] = -__expf(A_logs[((size_t)k * DI_ + d) * NS_ + n]);
  float S[NS_];
#pragma unroll
  for (int n = 0; n < NS_; ++n) S[n] = 0.f;
  float sum_dl = 0.f;
  size_t base = (size_t)bk * L_ + (size_t)c * LC_;
  for (int l = 0; l < LC_; ++l) {
    float dl = delta[(base + l) * DI_ + d];
    float u = xs[(base + l) * DI_ + d];
    float du = dl * u;
    sum_dl += dl;
    const float* Bp = Bsb + (base + l) * NS_;
#pragma unroll
    for (int n = 0; n < NS_; ++n) {
      float e = __expf(dl * A[n]);
      S[n] = e * S[n] + du * Bp[n];
    }
  }
  size_t ob = (size_t)blk * NS_ * DI_ + d;
#pragma unroll
  for (int n = 0; n < NS_; ++n) {
    Pbuf[ob + (size_t)n * DI_] = __expf(A[n] * sum_dl);
    SHin[ob + (size_t)n * DI_] = S[n];
  }
}

// ---------------------------------------------------------------------------
// K5b: chunk-level scan, parallel over (bk, n).  grid = B*K*NS = 192.
// SHin holds S on entry, h_in on exit (in-place).
// ---------------------------------------------------------------------------
__global__ void __launch_bounds__(192) k_scan2(
    const float* __restrict__ Pbuf, float* __restrict__ SHin) {
  int bkn = blockIdx.x;            // bk*NS + n
  int bk = bkn / NS_, n = bkn % NS_;
  int d = threadIdx.x;
  float h = 0.f;
  for (int c = 0; c < C_; ++c) {
    size_t i = ((size_t)(bk * C_ + c) * NS_ + n) * DI_ + d;
    float s = SHin[i];
    float p = Pbuf[i];
    SHin[i] = h;
    h = p * h + s;
  }
}

// ---------------------------------------------------------------------------
// K5c: chunked scan pass 3 — recompute from h_in, emit out_y.
// ---------------------------------------------------------------------------
__global__ void __launch_bounds__(192) k_scan3(
    const float* __restrict__ delta, const float* __restrict__ xs,
    const float* __restrict__ Bsb, const float* __restrict__ Csb,
    const float* __restrict__ A_logs, const float* __restrict__ Ds,
    const float* __restrict__ SHin, float* __restrict__ out_y) {
  int blk = blockIdx.x;            // bk*C_ + c
  int bk = blk / C_, c = blk % C_;
  int k = bk % K_;
  int d = threadIdx.x;
  float A[NS_];
#pragma unroll
  for (int n = 0; n < NS_; ++n) A[n] = -__expf(A_logs[((size_t)k * DI_ + d) * NS_ + n]);
  float Dk = Ds[k * DI_ + d];
  float h[NS_];
  size_t hb = (size_t)blk * NS_ * DI_ + d;
#pragma unroll
  for (int n = 0; n < NS_; ++n) h[n] = SHin[hb + (size_t)n * DI_];
  size_t base = (size_t)bk * L_ + (size_t)c * LC_;
  for (int l = 0; l < LC_; ++l) {
    float dl = delta[(base + l) * DI_ + d];
    float u = xs[(base + l) * DI_ + d];
    float du = dl * u;
    const float* Bp = Bsb + (base + l) * NS_;
    const float* Cp = Csb + (base + l) * NS_;
    float yacc = 0.f;
#pragma unroll
    for (int n = 0; n < NS_; ++n) {
      h[n] = __expf(dl * A[n]) * h[n] + du * Bp[n];
      yacc += h[n] * Cp[n];
    }
    out_y[(base + l) * DI_ + d] = yacc + Dk * u;
  }
}

// ---------------------------------------------------------------------------
// K6 fused: merge + LayerNorm + gate into LDS, then out-proj GEMM from LDS.
// grid = 3 * (B*L/64) = 216, block 256.
// ---------------------------------------------------------------------------
constexpr int MT = 64, GS_ = 196;   // Gs stride (mult of 4 for float4 LDS)
__global__ void __launch_bounds__(256) k_head2(
    const float* __restrict__ out_y, const float* __restrict__ zg,
    const float* __restrict__ lnw, const float* __restrict__ lnb,
    const float* __restrict__ wT, float* __restrict__ out) {
  __shared__ float Gs[MT][GS_];
  __shared__ float Ws[32][DM_ + 1];
  int tid = threadIdx.x;
  constexpr int BPS = (B_ * L_) / MT;  // 72
  int m = blockIdx.x / BPS;
  int r0 = (blockIdx.x % BPS) * MT;

  // ---- phase 1: 4 threads per row; merge + LN + gate -> Gs
  {
    int row = tid >> 2, t4 = tid & 3;
    int bl = r0 + row;
    int b = bl / L_, lp = bl % L_;
    int h = lp / W_, w = lp % W_;
    int l0;
    if (m == 0) l0 = lp;
    else if (m == 1) l0 = w * H_ + h;
    else l0 = ((w - h + W_) % W_) * H_ + h;
    size_t basef = ((size_t)b * K_ + m) * L_;
    size_t baser = ((size_t)b * K_ + m + 3) * L_;
    const float* pf = out_y + (basef + l0) * DI_;
    const float* pr = out_y + (baser + (size_t)(L_ - 1 - l0)) * DI_;
    float s = 0.f, s2 = 0.f;
#pragma unroll
    for (int j = 0; j < 12; ++j) {
      int c4 = t4 * 48 + j * 4;
      float4 a = *reinterpret_cast<const float4*>(&pf[c4]);
      float4 bb = *reinterpret_cast<const float4*>(&pr[c4]);
      float4 t;
      t.x = a.x + bb.x; t.y = a.y + bb.y; t.z = a.z + bb.z; t.w = a.w + bb.w;
      s += t.x + t.y + t.z + t.w;
      s2 += t.x * t.x + t.y * t.y + t.z * t.z + t.w * t.w;
      *reinterpret_cast<float4*>(&Gs[row][c4]) = t;
    }
    s += __shfl_xor(s, 1, 64);  s2 += __shfl_xor(s2, 1, 64);
    s += __shfl_xor(s, 2, 64);  s2 += __shfl_xor(s2, 2, 64);
    float mu = s * (1.f / DI_);
    float var = fmaxf(s2 * (1.f / DI_) - mu * mu, 0.f);
    float rs = rsqrtf(var + 1e-5f);
    const float* zp = zg + (size_t)bl * DI_;
#pragma unroll
    for (int j = 0; j < 12; ++j) {
      int c4 = t4 * 48 + j * 4;
      float4 t = *reinterpret_cast<const float4*>(&Gs[row][c4]);
      float4 zv = *reinterpret_cast<const float4*>(&zp[c4]);
      t.x = ((t.x - mu) * rs * lnw[c4 + 0] + lnb[c4 + 0]) * zv.x;
      t.y = ((t.y - mu) * rs * lnw[c4 + 1] + lnb[c4 + 1]) * zv.y;
      t.z = ((t.z - mu) * rs * lnw[c4 + 2] + lnb[c4 + 2]) * zv.z;
      t.w = ((t.w - mu) * rs * lnw[c4 + 3] + lnb[c4 + 3]) * zv.w;
      *reinterpret_cast<float4*>(&Gs[row][c4]) = t;
    }
  }
  __syncthreads();

  // ---- phase 2: GEMM  out[r0..r0+63][96] = Gs[64][192] * wT[192][96]
  int tm = tid >> 4, tn = tid & 15;
  float acc[4][6];
#pragma unroll
  for (int i = 0; i < 4; ++i)
#pragma unroll
    for (int j = 0; j < 6; ++j) acc[i][j] = 0.f;

  for (int k0 = 0; k0 < DI_; k0 += 32) {
#pragma unroll
    for (int it = 0; it < 3; ++it) {
      int i = tid + it * 256;
      int r = i / 24, c4 = (i % 24) << 2;
      const float4 v = *reinterpret_cast<const float4*>(
          &wT[(size_t)(k0 + r) * DM_ + c4]);
      Ws[r][c4] = v.x; Ws[r][c4 + 1] = v.y; Ws[r][c4 + 2] = v.z; Ws[r][c4 + 3] = v.w;
    }
    __syncthreads();
#pragma unroll
    for (int kk = 0; kk < 32; ++kk) {
      float a0 = Gs[tm * 4 + 0][k0 + kk], a1 = Gs[tm * 4 + 1][k0 + kk];
      float a2 = Gs[tm * 4 + 2][k0 + kk], a3 = Gs[tm * 4 + 3][k0 + kk];
      float w[6];
#pragma unroll
      for (int j = 0; j < 6; ++j) w[j] = Ws[kk][tn * 6 + j];
#pragma unroll
      for (int j = 0; j < 6; ++j) {
        acc[0][j] += a0 * w[j];
        acc[1][j] += a1 * w[j];
        acc[2][j] += a2 * w[j];
        acc[3][j] += a3 * w[j];
      }
    }
    __syncthreads();
  }
  size_t obase = ((size_t)m * (B_ * L_) + r0) * DM_;
#pragma unroll
  for (int i = 0; i < 4; ++i) {
    size_t ob = obase + (size_t)(tm * 4 + i) * DM_ + tn * 6;
#pragma unroll
    for (int j = 0; j < 6; ++j) out[ob + j] = acc[i][j];
  }
}

}  // namespace

extern "C" void kernel_launch(void* const* d_in, const int* in_sizes, int n_in,
                              void* d_out, int out_size, void* d_ws, size_t ws_size,
                              hipStream_t stream) {
  const float* x = (const float*)d_in[0];
  const float* y = (const float*)d_in[1];
  const float* kin = (const float*)d_in[2];
  const float* in_proj_w = (const float*)d_in[3];
  const float* conv_w = (const float*)d_in[4];
  const float* conv_b = (const float*)d_in[5];
  const float* x_proj_w = (const float*)d_in[6];
  const float* dt_w = (const float*)d_in[7];
  const float* dt_b = (const float*)d_in[8];
  const float* A_logs = (const float*)d_in[9];
  const float* Ds = (const float*)d_in[10];
  const float* ln_w = (const float*)d_in[11];
  const float* ln_b = (const float*)d_in[12];
  const float* out_proj_w = (const float*)d_in[13];
  float* out = (float*)d_out;

  float* ws = (float*)d_ws;
  const size_t BLD = (size_t)B_ * L_ * DI_;                 // 884736
  const size_t BKLD = (size_t)B_ * K_ * L_ * DI_;           // 5308416
  const size_t BKLN = (size_t)B_ * K_ * L_ * NS_;           // 442368
  const size_t PSN = (size_t)B_ * K_ * C_ * NS_ * DI_;      // 3538944 = 4*BLD
  float* xv = ws;             ws += BLD;
  float* yv = ws;             ws += BLD;
  /* pext */                  ws += 2 * BLD;
  float* zg = ws;             ws += BLD;
  float* xs = ws;             ws += BKLD;
  float* delta = ws;          ws += BKLD;
  float* Bsb = ws;            ws += BKLN;
  float* Csb = ws;            ws += BKLN;
  float* out_y = ws;          ws += BKLD;
  float* SHin = ws;           ws += PSN;
  float* wT = ws;             ws += (size_t)DI_ * DM_;
  float* xpwT = ws;           ws += (size_t)K_ * DI_ * NPAD;
  float* wInT = ws;           ws += (size_t)DM_ * 2 * DI_;
  float* dts = ws;            ws += (size_t)B_ * K_ * L_ * RK_;
  // alias onto dead region:
  float* Pbuf = xv;    // spans xv,yv,pext (4*BLD == PSN), dead after conv_xs

  dim3 blk(DI_);
  k_prep<<<DM_ + K_ + DI_, 384, 0, stream>>>(in_proj_w, x_proj_w, out_proj_w,
                                             wInT, xpwT, wT);
  k_inproj2<<<3 * B_ * L_ / IM, 256, 0, stream>>>(x, y, kin, wInT, xv, yv, zg);
  k_conv_xs<<<B_ * L_, blk, 0, stream>>>(xv, yv, conv_w, conv_b, xs);
  k_xdbl3<<<B_ * K_ * L_ / XM, 256, 0, stream>>>(xs, xpwT, dts, Bsb, Csb);
  k_delta<<<B_ * K_ * L_ / DR_, blk, 0, stream>>>(dts, dt_w, dt_b, delta);
  k_scan1<<<B_ * K_ * C_, blk, 0, stream>>>(delta, xs, Bsb, A_logs, Pbuf, SHin);
  k_scan2<<<B_ * K_ * NS_, blk, 0, stream>>>(Pbuf, SHin);
  k_scan3<<<B_ * K_ * C_, blk, 0, stream>>>(delta, xs, Bsb, Csb, A_logs, Ds, SHin, out_y);
  k_head2<<<3 * B_ * L_ / MT, 256, 0, stream>>>(out_y, zg, ln_w, ln_b, wT, out);
}

// Round 8
// 176.907 us; speedup vs baseline: 14.9651x; 1.0005x over previous
//
#include <hip/hip_runtime.h>
#include <hip/hip_bf16.h>

namespace {

constexpr int B_ = 2, H_ = 48, W_ = 48, DM_ = 96, DI_ = 192, NS_ = 16, RK_ = 6, K_ = 6;
constexpr int L_ = H_ * W_;
constexpr int C_ = 96;            // chunks per (b,k) stream
constexpr int LC_ = L_ / C_;      // 24 steps per chunk
constexpr int NPROJ = RK_ + 2 * NS_;  // 38
constexpr int NPAD = 48;              // padded N for the xdbl GEMM

__device__ __forceinline__ float sigmoidf_(float x) { return 1.f / (1.f + __expf(-x)); }

// softplus(dtb + dts(row)·dtw(d)) — MUST be evaluated identically in scan1
// and scan3 so both passes see bit-identical dl.
__device__ __forceinline__ float delta_of(const float* __restrict__ dp,
                                          const float* __restrict__ wdt,
                                          float bias) {
  float s = bias;
#pragma unroll
  for (int r = 0; r < RK_; ++r) s += dp[r] * wdt[r];
  return (s > 20.f) ? s : __logf(1.f + __expf(s));
}

// ---------------------------------------------------------------------------
// K0: all weight prep in one launch.
// ---------------------------------------------------------------------------
__global__ void k_prep(const float* __restrict__ Wp, const float* __restrict__ xpw,
                       const float* __restrict__ opw, float* __restrict__ wInT,
                       float* __restrict__ xpwT, float* __restrict__ wT) {
  int blk = blockIdx.x;
  int tid = threadIdx.x;
  if (blk < DM_) {
    wInT[(size_t)blk * (2 * DI_) + tid] = Wp[(size_t)tid * DM_ + blk];
  } else if (blk < DM_ + K_) {
    int k = blk - DM_;
    if (tid < DI_) {
      float* dst = xpwT + ((size_t)k * DI_ + tid) * NPAD;
      for (int c = 0; c < NPAD; ++c)
        dst[c] = (c < NPROJ) ? xpw[((size_t)k * NPROJ + c) * DI_ + tid] : 0.f;
    }
  } else {
    int c = blk - DM_ - K_;
    if (tid < DM_)
      wT[(size_t)c * DM_ + tid] = opw[(size_t)tid * DI_ + c];
  }
}

// ---------------------------------------------------------------------------
// K1: in_proj as tiled GEMM.  Streams s=0(x->xv), 1(y->yv), 2(k->silu->zg).
// ---------------------------------------------------------------------------
constexpr int IM = 64, IBK = 32;
__global__ void __launch_bounds__(256) k_inproj2(
    const float* __restrict__ x, const float* __restrict__ y,
    const float* __restrict__ kin, const float* __restrict__ wInT,
    float* __restrict__ xv, float* __restrict__ yv, float* __restrict__ zg) {
  __shared__ float As[IM][IBK + 1];
  __shared__ float Ws[IBK][DI_ + 1];
  int tid = threadIdx.x;
  constexpr int BPS = (B_ * L_) / IM;   // 72 blocks per stream
  int s = blockIdx.x / BPS;
  int row0 = (blockIdx.x % BPS) * IM;
  const float* src = (s == 0) ? x : (s == 1) ? y : kin;
  float* dst = (s == 0) ? xv : (s == 1) ? yv : zg;
  int nbase = (s == 2) ? DI_ : 0;
  int tm = tid >> 4, tn = tid & 15;     // 16 x 16
  float acc[4][12];
#pragma unroll
  for (int i = 0; i < 4; ++i)
#pragma unroll
    for (int j = 0; j < 12; ++j) acc[i][j] = 0.f;

  for (int k0 = 0; k0 < DM_; k0 += IBK) {
#pragma unroll
    for (int it = 0; it < 2; ++it) {
      int i = tid + it * 256;
      int r = i >> 3, c4 = (i & 7) << 2;
      const float4 v = *reinterpret_cast<const float4*>(
          &src[(size_t)(row0 + r) * DM_ + k0 + c4]);
      As[r][c4] = v.x; As[r][c4 + 1] = v.y; As[r][c4 + 2] = v.z; As[r][c4 + 3] = v.w;
    }
#pragma unroll
    for (int it = 0; it < 6; ++it) {
      int i = tid + it * 256;
      int r = i / 48, c4 = (i % 48) << 2;
      const float4 v = *reinterpret_cast<const float4*>(
          &wInT[(size_t)(k0 + r) * (2 * DI_) + nbase + c4]);
      Ws[r][c4] = v.x; Ws[r][c4 + 1] = v.y; Ws[r][c4 + 2] = v.z; Ws[r][c4 + 3] = v.w;
    }
    __syncthreads();
#pragma unroll
    for (int kk = 0; kk < IBK; ++kk) {
      float a[4];
#pragma unroll
      for (int i = 0; i < 4; ++i) a[i] = As[tm * 4 + i][kk];
      float w[12];
#pragma unroll
      for (int j = 0; j < 12; ++j) w[j] = Ws[kk][tn * 12 + j];
#pragma unroll
      for (int i = 0; i < 4; ++i)
#pragma unroll
        for (int j = 0; j < 12; ++j) acc[i][j] += a[i] * w[j];
    }
    __syncthreads();
  }
#pragma unroll
  for (int i = 0; i < 4; ++i) {
    size_t ob = (size_t)(row0 + tm * 4 + i) * DI_ + tn * 12;
#pragma unroll
    for (int j = 0; j < 12; ++j) {
      float v = acc[i][j];
      if (s == 2) v = v * sigmoidf_(v);
      dst[ob + j] = v;
    }
  }
}

// ---------------------------------------------------------------------------
// K2+K3 fused: depthwise 3x3 conv + SiLU on xv AND yv, scatter into 6 streams.
// ---------------------------------------------------------------------------
__global__ void __launch_bounds__(192) k_conv_xs(
    const float* __restrict__ xv, const float* __restrict__ yv,
    const float* __restrict__ cw, const float* __restrict__ cb,
    float* __restrict__ xs) {
  int bl = blockIdx.x;
  int d = threadIdx.x;
  int b = bl / L_, l = bl % L_;
  int h = l / W_, w = l % W_;
  float bias = cb[d];
  float ax = bias, ay = bias;
  const float* wp = cw + d * 9;
#pragma unroll
  for (int kh = 0; kh < 3; ++kh) {
    int hh = h + kh - 1;
    if (hh < 0 || hh >= H_) continue;
#pragma unroll
    for (int kw = 0; kw < 3; ++kw) {
      int ww = w + kw - 1;
      if (ww < 0 || ww >= W_) continue;
      float wk = wp[kh * 3 + kw];
      size_t idx = ((size_t)b * L_ + hh * W_ + ww) * DI_ + d;
      ax += xv[idx] * wk;
      ay += yv[idx] * wk;
    }
  }
  ax = ax * sigmoidf_(ax);
  ay = ay * sigmoidf_(ay);
  size_t base = (size_t)b * K_ * L_;
  int lv = w * H_ + h;
  int w2 = (w - h + W_) % W_;
  int lv2 = w2 * H_ + h;
  xs[(base + (size_t)0 * L_ + l) * DI_ + d] = ax;
  xs[(base + (size_t)3 * L_ + (L_ - 1 - l)) * DI_ + d] = ax;
  xs[(base + (size_t)1 * L_ + lv) * DI_ + d] = ay;
  xs[(base + (size_t)4 * L_ + (L_ - 1 - lv)) * DI_ + d] = ay;
  xs[(base + (size_t)2 * L_ + lv2) * DI_ + d] = ay;
  xs[(base + (size_t)5 * L_ + (L_ - 1 - lv2)) * DI_ + d] = ay;
}

// ---------------------------------------------------------------------------
// K4: x_dbl GEMM.  M tiles of 32, N = 48(pad of 38), K = 192.
// ---------------------------------------------------------------------------
constexpr int XM = 32, XBK = 32;
__global__ void __launch_bounds__(256) k_xdbl3(
    const float* __restrict__ xs, const float* __restrict__ xpwT,
    float* __restrict__ dts, float* __restrict__ Bsb, float* __restrict__ Csb) {
  __shared__ float As[XM][XBK + 1];
  __shared__ float Ws[XBK][NPAD];
  int tid = threadIdx.x;
  int row0 = blockIdx.x * XM;
  int k = (row0 / L_) % K_;
  int tm = tid >> 4, tn = tid & 15;
  float acc[2][3];
#pragma unroll
  for (int i = 0; i < 2; ++i)
#pragma unroll
    for (int j = 0; j < 3; ++j) acc[i][j] = 0.f;

  for (int k0 = 0; k0 < DI_; k0 += XBK) {
    {
      int r = tid >> 3, c4 = (tid & 7) << 2;
      const float4 v = *reinterpret_cast<const float4*>(
          &xs[(size_t)(row0 + r) * DI_ + k0 + c4]);
      As[r][c4] = v.x; As[r][c4 + 1] = v.y; As[r][c4 + 2] = v.z; As[r][c4 + 3] = v.w;
    }
#pragma unroll
    for (int it = 0; it < 2; ++it) {
      int i = tid + it * 256;
      if (i < 384) {
        int r = i / 12, c4 = (i % 12) << 2;
        const float4 v = *reinterpret_cast<const float4*>(
            &xpwT[((size_t)k * DI_ + k0 + r) * NPAD + c4]);
        Ws[r][c4] = v.x; Ws[r][c4 + 1] = v.y; Ws[r][c4 + 2] = v.z; Ws[r][c4 + 3] = v.w;
      }
    }
    __syncthreads();
#pragma unroll
    for (int kk = 0; kk < XBK; ++kk) {
      float a0 = As[tm * 2 + 0][kk], a1 = As[tm * 2 + 1][kk];
      float w0 = Ws[kk][tn * 3 + 0], w1 = Ws[kk][tn * 3 + 1], w2 = Ws[kk][tn * 3 + 2];
      acc[0][0] += a0 * w0; acc[0][1] += a0 * w1; acc[0][2] += a0 * w2;
      acc[1][0] += a1 * w0; acc[1][1] += a1 * w1; acc[1][2] += a1 * w2;
    }
    __syncthreads();
  }
#pragma unroll
  for (int i = 0; i < 2; ++i) {
    int row = row0 + tm * 2 + i;
#pragma unroll
    for (int j = 0; j < 3; ++j) {
      int cc = tn * 3 + j;
      float v = acc[i][j];
      if (cc < RK_) dts[(size_t)row * RK_ + cc] = v;
      else if (cc < RK_ + NS_) Bsb[(size_t)row * NS_ + (cc - RK_)] = v;
      else if (cc < NPROJ) Csb[(size_t)row * NS_ + (cc - RK_ - NS_)] = v;
    }
  }
}

// ---------------------------------------------------------------------------
// K5a: chunked scan pass 1.  dl recomputed from dts (no delta tensor).
// Writes S (SHin) and sum_dl (Sdl).  grid = B*K*C_ = 1152, 192 thr.
// ---------------------------------------------------------------------------
__global__ void __launch_bounds__(192) k_scan1(
    const float* __restrict__ dts, const float* __restrict__ dtw,
    const float* __restrict__ dtb, const float* __restrict__ xs,
    const float* __restrict__ Bsb, const float* __restrict__ A_logs,
    float* __restrict__ Sdl, float* __restrict__ SHin) {
  int blk = blockIdx.x;            // bk*C_ + c
  int bk = blk / C_, c = blk % C_;
  int k = bk % K_;
  int d = threadIdx.x;
  float A[NS_];
#pragma unroll
  for (int n = 0; n < NS_; ++n) A[n] = -__expf(A_logs[((size_t)k * DI_ + d) * NS_ + n]);
  float wdt[RK_];
#pragma unroll
  for (int r = 0; r < RK_; ++r) wdt[r] = dtw[((size_t)k * DI_ + d) * RK_ + r];
  float bias = dtb[k * DI_ + d];
  float S[NS_];
#pragma unroll
  for (int n = 0; n < NS_; ++n) S[n] = 0.f;
  float sum_dl = 0.f;
  size_t base = (size_t)bk * L_ + (size_t)c * LC_;
  for (int l = 0; l < LC_; ++l) {
    float dl = delta_of(dts + (base + l) * RK_, wdt, bias);
    float u = xs[(base + l) * DI_ + d];
    float du = dl * u;
    sum_dl += dl;
    const float* Bp = Bsb + (base + l) * NS_;
#pragma unroll
    for (int n = 0; n < NS_; ++n) {
      float e = __expf(dl * A[n]);
      S[n] = e * S[n] + du * Bp[n];
    }
  }
  Sdl[(size_t)blk * DI_ + d] = sum_dl;
  size_t ob = (size_t)blk * NS_ * DI_ + d;
#pragma unroll
  for (int n = 0; n < NS_; ++n) SHin[ob + (size_t)n * DI_] = S[n];
}

// ---------------------------------------------------------------------------
// K5b: chunk-level scan, parallel over (bk, n).  grid = B*K*NS = 192.
// P recomputed as exp(A*sum_dl).  SHin: S in, h_in out (in-place).
// ---------------------------------------------------------------------------
__global__ void __launch_bounds__(192) k_scan2(
    const float* __restrict__ Sdl, const float* __restrict__ A_logs,
    float* __restrict__ SHin) {
  int bkn = blockIdx.x;            // bk*NS + n
  int bk = bkn / NS_, n = bkn % NS_;
  int k = bk % K_;
  int d = threadIdx.x;
  float A = -__expf(A_logs[((size_t)k * DI_ + d) * NS_ + n]);
  float h = 0.f;
  for (int c = 0; c < C_; ++c) {
    size_t i = ((size_t)(bk * C_ + c) * NS_ + n) * DI_ + d;
    float s = SHin[i];
    float p = __expf(A * Sdl[(size_t)(bk * C_ + c) * DI_ + d]);
    SHin[i] = h;
    h = p * h + s;
  }
}

// ---------------------------------------------------------------------------
// K5c: chunked scan pass 3 — recompute dl from dts, start from h_in, emit out_y.
// ---------------------------------------------------------------------------
__global__ void __launch_bounds__(192) k_scan3(
    const float* __restrict__ dts, const float* __restrict__ dtw,
    const float* __restrict__ dtb, const float* __restrict__ xs,
    const float* __restrict__ Bsb, const float* __restrict__ Csb,
    const float* __restrict__ A_logs, const float* __restrict__ Ds,
    const float* __restrict__ SHin, float* __restrict__ out_y) {
  int blk = blockIdx.x;            // bk*C_ + c
  int bk = blk / C_, c = blk % C_;
  int k = bk % K_;
  int d = threadIdx.x;
  float A[NS_];
#pragma unroll
  for (int n = 0; n < NS_; ++n) A[n] = -__expf(A_logs[((size_t)k * DI_ + d) * NS_ + n]);
  float wdt[RK_];
#pragma unroll
  for (int r = 0; r < RK_; ++r) wdt[r] = dtw[((size_t)k * DI_ + d) * RK_ + r];
  float bias = dtb[k * DI_ + d];
  float Dk = Ds[k * DI_ + d];
  float h[NS_];
  size_t hb = (size_t)blk * NS_ * DI_ + d;
#pragma unroll
  for (int n = 0; n < NS_; ++n) h[n] = SHin[hb + (size_t)n * DI_];
  size_t base = (size_t)bk * L_ + (size_t)c * LC_;
  for (int l = 0; l < LC_; ++l) {
    float dl = delta_of(dts + (base + l) * RK_, wdt, bias);
    float u = xs[(base + l) * DI_ + d];
    float du = dl * u;
    const float* Bp = Bsb + (base + l) * NS_;
    const float* Cp = Csb + (base + l) * NS_;
    float yacc = 0.f;
#pragma unroll
    for (int n = 0; n < NS_; ++n) {
      h[n] = __expf(dl * A[n]) * h[n] + du * Bp[n];
      yacc += h[n] * Cp[n];
    }
    out_y[(base + l) * DI_ + d] = yacc + Dk * u;
  }
}

// ---------------------------------------------------------------------------
// K6 fused: merge + LayerNorm + gate into LDS, then out-proj GEMM from LDS.
// ---------------------------------------------------------------------------
constexpr int MT = 64, GS_ = 196;
__global__ void __launch_bounds__(256) k_head2(
    const float* __restrict__ out_y, const float* __restrict__ zg,
    const float* __restrict__ lnw, const float* __restrict__ lnb,
    const float* __restrict__ wT, float* __restrict__ out) {
  __shared__ float Gs[MT][GS_];
  __shared__ float Ws[32][DM_ + 1];
  int tid = threadIdx.x;
  constexpr int BPS = (B_ * L_) / MT;  // 72
  int m = blockIdx.x / BPS;
  int r0 = (blockIdx.x % BPS) * MT;

  {
    int row = tid >> 2, t4 = tid & 3;
    int bl = r0 + row;
    int b = bl / L_, lp = bl % L_;
    int h = lp / W_, w = lp % W_;
    int l0;
    if (m == 0) l0 = lp;
    else if (m == 1) l0 = w * H_ + h;
    else l0 = ((w - h + W_) % W_) * H_ + h;
    size_t basef = ((size_t)b * K_ + m) * L_;
    size_t baser = ((size_t)b * K_ + m + 3) * L_;
    const float* pf = out_y + (basef + l0) * DI_;
    const float* pr = out_y + (baser + (size_t)(L_ - 1 - l0)) * DI_;
    float s = 0.f, s2 = 0.f;
#pragma unroll
    for (int j = 0; j < 12; ++j) {
      int c4 = t4 * 48 + j * 4;
      float4 a = *reinterpret_cast<const float4*>(&pf[c4]);
      float4 bb = *reinterpret_cast<const float4*>(&pr[c4]);
      float4 t;
      t.x = a.x + bb.x; t.y = a.y + bb.y; t.z = a.z + bb.z; t.w = a.w + bb.w;
      s += t.x + t.y + t.z + t.w;
      s2 += t.x * t.x + t.y * t.y + t.z * t.z + t.w * t.w;
      *reinterpret_cast<float4*>(&Gs[row][c4]) = t;
    }
    s += __shfl_xor(s, 1, 64);  s2 += __shfl_xor(s2, 1, 64);
    s += __shfl_xor(s, 2, 64);  s2 += __shfl_xor(s2, 2, 64);
    float mu = s * (1.f / DI_);
    float var = fmaxf(s2 * (1.f / DI_) - mu * mu, 0.f);
    float rs = rsqrtf(var + 1e-5f);
    const float* zp = zg + (size_t)bl * DI_;
#pragma unroll
    for (int j = 0; j < 12; ++j) {
      int c4 = t4 * 48 + j * 4;
      float4 t = *reinterpret_cast<const float4*>(&Gs[row][c4]);
      float4 zv = *reinterpret_cast<const float4*>(&zp[c4]);
      t.x = ((t.x - mu) * rs * lnw[c4 + 0] + lnb[c4 + 0]) * zv.x;
      t.y = ((t.y - mu) * rs * lnw[c4 + 1] + lnb[c4 + 1]) * zv.y;
      t.z = ((t.z - mu) * rs * lnw[c4 + 2] + lnb[c4 + 2]) * zv.z;
      t.w = ((t.w - mu) * rs * lnw[c4 + 3] + lnb[c4 + 3]) * zv.w;
      *reinterpret_cast<float4*>(&Gs[row][c4]) = t;
    }
  }
  __syncthreads();

  int tm = tid >> 4, tn = tid & 15;
  float acc[4][6];
#pragma unroll
  for (int i = 0; i < 4; ++i)
#pragma unroll
    for (int j = 0; j < 6; ++j) acc[i][j] = 0.f;

  for (int k0 = 0; k0 < DI_; k0 += 32) {
#pragma unroll
    for (int it = 0; it < 3; ++it) {
      int i = tid + it * 256;
      int r = i / 24, c4 = (i % 24) << 2;
      const float4 v = *reinterpret_cast<const float4*>(
          &wT[(size_t)(k0 + r) * DM_ + c4]);
      Ws[r][c4] = v.x; Ws[r][c4 + 1] = v.y; Ws[r][c4 + 2] = v.z; Ws[r][c4 + 3] = v.w;
    }
    __syncthreads();
#pragma unroll
    for (int kk = 0; kk < 32; ++kk) {
      float a0 = Gs[tm * 4 + 0][k0 + kk], a1 = Gs[tm * 4 + 1][k0 + kk];
      float a2 = Gs[tm * 4 + 2][k0 + kk], a3 = Gs[tm * 4 + 3][k0 + kk];
      float w[6];
#pragma unroll
      for (int j = 0; j < 6; ++j) w[j] = Ws[kk][tn * 6 + j];
#pragma unroll
      for (int j = 0; j < 6; ++j) {
        acc[0][j] += a0 * w[j];
        acc[1][j] += a1 * w[j];
        acc[2][j] += a2 * w[j];
        acc[3][j] += a3 * w[j];
      }
    }
    __syncthreads();
  }
  size_t obase = ((size_t)m * (B_ * L_) + r0) * DM_;
#pragma unroll
  for (int i = 0; i < 4; ++i) {
    size_t ob = obase + (size_t)(tm * 4 + i) * DM_ + tn * 6;
#pragma unroll
    for (int j = 0; j < 6; ++j) out[ob + j] = acc[i][j];
  }
}

}  // namespace

extern "C" void kernel_launch(void* const* d_in, const int* in_sizes, int n_in,
                              void* d_out, int out_size, void* d_ws, size_t ws_size,
                              hipStream_t stream) {
  const float* x = (const float*)d_in[0];
  const float* y = (const float*)d_in[1];
  const float* kin = (const float*)d_in[2];
  const float* in_proj_w = (const float*)d_in[3];
  const float* conv_w = (const float*)d_in[4];
  const float* conv_b = (const float*)d_in[5];
  const float* x_proj_w = (const float*)d_in[6];
  const float* dt_w = (const float*)d_in[7];
  const float* dt_b = (const float*)d_in[8];
  const float* A_logs = (const float*)d_in[9];
  const float* Ds = (const float*)d_in[10];
  const float* ln_w = (const float*)d_in[11];
  const float* ln_b = (const float*)d_in[12];
  const float* out_proj_w = (const float*)d_in[13];
  float* out = (float*)d_out;

  float* ws = (float*)d_ws;
  const size_t BLD = (size_t)B_ * L_ * DI_;                 // 884736
  const size_t BKLD = (size_t)B_ * K_ * L_ * DI_;           // 5308416
  const size_t BKLN = (size_t)B_ * K_ * L_ * NS_;           // 442368
  const size_t PSN = (size_t)B_ * K_ * C_ * NS_ * DI_;      // 3538944
  float* xv = ws;             ws += BLD;
  float* yv = ws;             ws += BLD;
  float* zg = ws;             ws += BLD;
  float* xs = ws;             ws += BKLD;
  float* Bsb = ws;            ws += BKLN;
  float* Csb = ws;            ws += BKLN;
  float* out_y = ws;          ws += BKLD;
  float* SHin = ws;           ws += PSN;
  float* Sdl = ws;            ws += (size_t)B_ * K_ * C_ * DI_;
  float* wT = ws;             ws += (size_t)DI_ * DM_;
  float* xpwT = ws;           ws += (size_t)K_ * DI_ * NPAD;
  float* wInT = ws;           ws += (size_t)DM_ * 2 * DI_;
  float* dts = ws;            ws += (size_t)B_ * K_ * L_ * RK_;

  dim3 blk(DI_);
  k_prep<<<DM_ + K_ + DI_, 384, 0, stream>>>(in_proj_w, x_proj_w, out_proj_w,
                                             wInT, xpwT, wT);
  k_inproj2<<<3 * B_ * L_ / IM, 256, 0, stream>>>(x, y, kin, wInT, xv, yv, zg);
  k_conv_xs<<<B_ * L_, blk, 0, stream>>>(xv, yv, conv_w, conv_b, xs);
  k_xdbl3<<<B_ * K_ * L_ / XM, 256, 0, stream>>>(xs, xpwT, dts, Bsb, Csb);
  k_scan1<<<B_ * K_ * C_, blk, 0, stream>>>(dts, dt_w, dt_b, xs, Bsb, A_logs, Sdl, SHin);
  k_scan2<<<B_ * K_ * NS_, blk, 0, stream>>>(Sdl, A_logs, SHin);
  k_scan3<<<B_ * K_ * C_, blk, 0, stream>>>(dts, dt_w, dt_b, xs, Bsb, Csb, A_logs,
                                            Ds, SHin, out_y);
  k_head2<<<3 * B_ * L_ / MT, 256, 0, stream>>>(out_y, zg, ln_w, ln_b, wT, out);
}

// Round 9
// 172.564 us; speedup vs baseline: 15.3417x; 1.0252x over previous
//
#include <hip/hip_runtime.h>
#include <hip/hip_bf16.h>

namespace {

constexpr int B_ = 2, H_ = 48, W_ = 48, DM_ = 96, DI_ = 192, NS_ = 16, RK_ = 6, K_ = 6;
constexpr int L_ = H_ * W_;
constexpr int C_ = 144;           // chunks per (b,k) stream
constexpr int LC_ = L_ / C_;      // 16 steps per chunk
constexpr int NPROJ = RK_ + 2 * NS_;  // 38
constexpr int NPAD = 48;              // padded N for the xdbl GEMM

__device__ __forceinline__ float sigmoidf_(float x) { return 1.f / (1.f + __expf(-x)); }

// softplus(dtb + dts(row)·dtw(d)) — evaluated identically in scan1 and scan3.
__device__ __forceinline__ float delta_of(const float* __restrict__ dp,
                                          const float* __restrict__ wdt,
                                          float bias) {
  float s = bias;
#pragma unroll
  for (int r = 0; r < RK_; ++r) s += dp[r] * wdt[r];
  return (s > 20.f) ? s : __logf(1.f + __expf(s));
}

// ---------------------------------------------------------------------------
// K0: all weight prep in one launch.  grid = 96 + 6 + 192 + 1 = 295, block 384.
// ---------------------------------------------------------------------------
__global__ void k_prep(const float* __restrict__ Wp, const float* __restrict__ xpw,
                       const float* __restrict__ opw, const float* __restrict__ cw,
                       float* __restrict__ wInT, float* __restrict__ xpwT,
                       float* __restrict__ wT, float* __restrict__ cwT) {
  int blk = blockIdx.x;
  int tid = threadIdx.x;
  if (blk < DM_) {
    wInT[(size_t)blk * (2 * DI_) + tid] = Wp[(size_t)tid * DM_ + blk];
  } else if (blk < DM_ + K_) {
    int k = blk - DM_;
    if (tid < DI_) {
      float* dst = xpwT + ((size_t)k * DI_ + tid) * NPAD;
      for (int c = 0; c < NPAD; ++c)
        dst[c] = (c < NPROJ) ? xpw[((size_t)k * NPROJ + c) * DI_ + tid] : 0.f;
    }
  } else if (blk < DM_ + K_ + DI_) {
    int c = blk - DM_ - K_;
    if (tid < DM_)
      wT[(size_t)c * DM_ + tid] = opw[(size_t)tid * DI_ + c];
  } else {
    if (tid < DI_) {
#pragma unroll
      for (int j = 0; j < 9; ++j) cwT[j * DI_ + tid] = cw[tid * 9 + j];
    }
  }
}

// ---------------------------------------------------------------------------
// K1: in_proj tiled GEMM.  IM=32 -> grid 432, block 256.
// ---------------------------------------------------------------------------
constexpr int IM = 32, IBK = 32;
__global__ void __launch_bounds__(256) k_inproj2(
    const float* __restrict__ x, const float* __restrict__ y,
    const float* __restrict__ kin, const float* __restrict__ wInT,
    float* __restrict__ xv, float* __restrict__ yv, float* __restrict__ zg) {
  __shared__ float As[IM][IBK + 1];
  __shared__ float Ws[IBK][DI_ + 1];
  int tid = threadIdx.x;
  constexpr int BPS = (B_ * L_) / IM;   // 144 blocks per stream
  int s = blockIdx.x / BPS;
  int row0 = (blockIdx.x % BPS) * IM;
  const float* src = (s == 0) ? x : (s == 1) ? y : kin;
  float* dst = (s == 0) ? xv : (s == 1) ? yv : zg;
  int nbase = (s == 2) ? DI_ : 0;
  int tm = tid >> 4, tn = tid & 15;     // 16 x 16
  float acc[2][12];
#pragma unroll
  for (int i = 0; i < 2; ++i)
#pragma unroll
    for (int j = 0; j < 12; ++j) acc[i][j] = 0.f;

  for (int k0 = 0; k0 < DM_; k0 += IBK) {
    {  // A tile: 32x32 = 256 float4, 1/thread
      int r = tid >> 3, c4 = (tid & 7) << 2;
      const float4 v = *reinterpret_cast<const float4*>(
          &src[(size_t)(row0 + r) * DM_ + k0 + c4]);
      As[r][c4] = v.x; As[r][c4 + 1] = v.y; As[r][c4 + 2] = v.z; As[r][c4 + 3] = v.w;
    }
#pragma unroll
    for (int it = 0; it < 6; ++it) {   // W tile: 32x192 = 1536 float4
      int i = tid + it * 256;
      int r = i / 48, c4 = (i % 48) << 2;
      const float4 v = *reinterpret_cast<const float4*>(
          &wInT[(size_t)(k0 + r) * (2 * DI_) + nbase + c4]);
      Ws[r][c4] = v.x; Ws[r][c4 + 1] = v.y; Ws[r][c4 + 2] = v.z; Ws[r][c4 + 3] = v.w;
    }
    __syncthreads();
#pragma unroll
    for (int kk = 0; kk < IBK; ++kk) {
      float a0 = As[tm * 2 + 0][kk], a1 = As[tm * 2 + 1][kk];
      float w[12];
#pragma unroll
      for (int j = 0; j < 12; ++j) w[j] = Ws[kk][tn * 12 + j];
#pragma unroll
      for (int j = 0; j < 12; ++j) {
        acc[0][j] += a0 * w[j];
        acc[1][j] += a1 * w[j];
      }
    }
    __syncthreads();
  }
#pragma unroll
  for (int i = 0; i < 2; ++i) {
    size_t ob = (size_t)(row0 + tm * 2 + i) * DI_ + tn * 12;
#pragma unroll
    for (int j4 = 0; j4 < 3; ++j4) {
      float4 v;
      v.x = acc[i][j4 * 4 + 0]; v.y = acc[i][j4 * 4 + 1];
      v.z = acc[i][j4 * 4 + 2]; v.w = acc[i][j4 * 4 + 3];
      if (s == 2) {
        v.x *= sigmoidf_(v.x); v.y *= sigmoidf_(v.y);
        v.z *= sigmoidf_(v.z); v.w *= sigmoidf_(v.w);
      }
      *reinterpret_cast<float4*>(&dst[ob + j4 * 4]) = v;
    }
  }
}

// ---------------------------------------------------------------------------
// K2: conv 3x3 + SiLU, float4-vectorized, 4 pixels/block.  grid = B*L/4 = 1152.
// ---------------------------------------------------------------------------
__global__ void __launch_bounds__(192) k_conv_xs(
    const float* __restrict__ xv, const float* __restrict__ yv,
    const float* __restrict__ cwT, const float* __restrict__ cb,
    float* __restrict__ xs) {
  int tid = threadIdx.x;
  int p = tid / 48, q = tid % 48;
  int gl = blockIdx.x * 4 + p;
  int b = gl / L_, l = gl % L_;
  int h = l / W_, w = l % W_;
  int d4 = q << 2;
  float4 ax = *reinterpret_cast<const float4*>(&cb[d4]);
  float4 ay = ax;
#pragma unroll
  for (int kh = 0; kh < 3; ++kh) {
    int hh = h + kh - 1;
    if ((unsigned)hh >= (unsigned)H_) continue;
#pragma unroll
    for (int kw = 0; kw < 3; ++kw) {
      int ww = w + kw - 1;
      if ((unsigned)ww >= (unsigned)W_) continue;
      float4 wk = *reinterpret_cast<const float4*>(&cwT[(kh * 3 + kw) * DI_ + d4]);
      size_t idx = ((size_t)b * L_ + hh * W_ + ww) * DI_ + d4;
      float4 vx = *reinterpret_cast<const float4*>(&xv[idx]);
      float4 vy = *reinterpret_cast<const float4*>(&yv[idx]);
      ax.x += vx.x * wk.x; ax.y += vx.y * wk.y; ax.z += vx.z * wk.z; ax.w += vx.w * wk.w;
      ay.x += vy.x * wk.x; ay.y += vy.y * wk.y; ay.z += vy.z * wk.z; ay.w += vy.w * wk.w;
    }
  }
  ax.x *= sigmoidf_(ax.x); ax.y *= sigmoidf_(ax.y);
  ax.z *= sigmoidf_(ax.z); ax.w *= sigmoidf_(ax.w);
  ay.x *= sigmoidf_(ay.x); ay.y *= sigmoidf_(ay.y);
  ay.z *= sigmoidf_(ay.z); ay.w *= sigmoidf_(ay.w);
  size_t base = (size_t)b * K_ * L_;
  int lv = w * H_ + h;
  int lv2 = ((w - h + W_) % W_) * H_ + h;
#define STORE6(kk, pos, val) \
  *reinterpret_cast<float4*>(&xs[(base + (size_t)(kk) * L_ + (pos)) * DI_ + d4]) = (val)
  STORE6(0, l, ax);
  STORE6(3, L_ - 1 - l, ax);
  STORE6(1, lv, ay);
  STORE6(4, L_ - 1 - lv, ay);
  STORE6(2, lv2, ay);
  STORE6(5, L_ - 1 - lv2, ay);
#undef STORE6
}

// ---------------------------------------------------------------------------
// K4: x_dbl GEMM.  M tiles of 32, N = 48(pad of 38), K = 192.  grid 864.
// ---------------------------------------------------------------------------
constexpr int XM = 32, XBK = 32;
__global__ void __launch_bounds__(256) k_xdbl3(
    const float* __restrict__ xs, const float* __restrict__ xpwT,
    float* __restrict__ dts, float* __restrict__ Bsb, float* __restrict__ Csb) {
  __shared__ float As[XM][XBK + 1];
  __shared__ float Ws[XBK][NPAD];
  int tid = threadIdx.x;
  int row0 = blockIdx.x * XM;
  int k = (row0 / L_) % K_;
  int tm = tid >> 4, tn = tid & 15;
  float acc[2][3];
#pragma unroll
  for (int i = 0; i < 2; ++i)
#pragma unroll
    for (int j = 0; j < 3; ++j) acc[i][j] = 0.f;

  for (int k0 = 0; k0 < DI_; k0 += XBK) {
    {
      int r = tid >> 3, c4 = (tid & 7) << 2;
      const float4 v = *reinterpret_cast<const float4*>(
          &xs[(size_t)(row0 + r) * DI_ + k0 + c4]);
      As[r][c4] = v.x; As[r][c4 + 1] = v.y; As[r][c4 + 2] = v.z; As[r][c4 + 3] = v.w;
    }
#pragma unroll
    for (int it = 0; it < 2; ++it) {
      int i = tid + it * 256;
      if (i < 384) {
        int r = i / 12, c4 = (i % 12) << 2;
        const float4 v = *reinterpret_cast<const float4*>(
            &xpwT[((size_t)k * DI_ + k0 + r) * NPAD + c4]);
        Ws[r][c4] = v.x; Ws[r][c4 + 1] = v.y; Ws[r][c4 + 2] = v.z; Ws[r][c4 + 3] = v.w;
      }
    }
    __syncthreads();
#pragma unroll
    for (int kk = 0; kk < XBK; ++kk) {
      float a0 = As[tm * 2 + 0][kk], a1 = As[tm * 2 + 1][kk];
      float w0 = Ws[kk][tn * 3 + 0], w1 = Ws[kk][tn * 3 + 1], w2 = Ws[kk][tn * 3 + 2];
      acc[0][0] += a0 * w0; acc[0][1] += a0 * w1; acc[0][2] += a0 * w2;
      acc[1][0] += a1 * w0; acc[1][1] += a1 * w1; acc[1][2] += a1 * w2;
    }
    __syncthreads();
  }
#pragma unroll
  for (int i = 0; i < 2; ++i) {
    int row = row0 + tm * 2 + i;
#pragma unroll
    for (int j = 0; j < 3; ++j) {
      int cc = tn * 3 + j;
      float v = acc[i][j];
      if (cc < RK_) dts[(size_t)row * RK_ + cc] = v;
      else if (cc < RK_ + NS_) Bsb[(size_t)row * NS_ + (cc - RK_)] = v;
      else if (cc < NPROJ) Csb[(size_t)row * NS_ + (cc - RK_ - NS_)] = v;
    }
  }
}

// ---------------------------------------------------------------------------
// K5a: chunked scan pass 1.  grid = B*K*C_ = 1728, 192 thr.
// ---------------------------------------------------------------------------
__global__ void __launch_bounds__(192) k_scan1(
    const float* __restrict__ dts, const float* __restrict__ dtw,
    const float* __restrict__ dtb, const float* __restrict__ xs,
    const float* __restrict__ Bsb, const float* __restrict__ A_logs,
    float* __restrict__ Sdl, float* __restrict__ SHin) {
  int blk = blockIdx.x;            // bk*C_ + c
  int bk = blk / C_, c = blk % C_;
  int k = bk % K_;
  int d = threadIdx.x;
  float A[NS_];
#pragma unroll
  for (int n = 0; n < NS_; ++n) A[n] = -__expf(A_logs[((size_t)k * DI_ + d) * NS_ + n]);
  float wdt[RK_];
#pragma unroll
  for (int r = 0; r < RK_; ++r) wdt[r] = dtw[((size_t)k * DI_ + d) * RK_ + r];
  float bias = dtb[k * DI_ + d];
  float S[NS_];
#pragma unroll
  for (int n = 0; n < NS_; ++n) S[n] = 0.f;
  float sum_dl = 0.f;
  size_t base = (size_t)bk * L_ + (size_t)c * LC_;
  for (int l = 0; l < LC_; ++l) {
    float dl = delta_of(dts + (base + l) * RK_, wdt, bias);
    float u = xs[(base + l) * DI_ + d];
    float du = dl * u;
    sum_dl += dl;
    const float* Bp = Bsb + (base + l) * NS_;
#pragma unroll
    for (int n = 0; n < NS_; ++n) {
      float e = __expf(dl * A[n]);
      S[n] = e * S[n] + du * Bp[n];
    }
  }
  Sdl[(size_t)blk * DI_ + d] = sum_dl;
  size_t ob = (size_t)blk * NS_ * DI_ + d;
#pragma unroll
  for (int n = 0; n < NS_; ++n) SHin[ob + (size_t)n * DI_] = S[n];
}

// ---------------------------------------------------------------------------
// K5b: chunk-level scan, parallel over (bk, n).  grid = B*K*NS = 192.
// ---------------------------------------------------------------------------
__global__ void __launch_bounds__(192) k_scan2(
    const float* __restrict__ Sdl, const float* __restrict__ A_logs,
    float* __restrict__ SHin) {
  int bkn = blockIdx.x;            // bk*NS + n
  int bk = bkn / NS_, n = bkn % NS_;
  int k = bk % K_;
  int d = threadIdx.x;
  float A = -__expf(A_logs[((size_t)k * DI_ + d) * NS_ + n]);
  float h = 0.f;
  for (int c = 0; c < C_; ++c) {
    size_t i = ((size_t)(bk * C_ + c) * NS_ + n) * DI_ + d;
    float s = SHin[i];
    float p = __expf(A * Sdl[(size_t)(bk * C_ + c) * DI_ + d]);
    SHin[i] = h;
    h = p * h + s;
  }
}

// ---------------------------------------------------------------------------
// K5c: chunked scan pass 3.  grid = 1728, 192 thr.
// ---------------------------------------------------------------------------
__global__ void __launch_bounds__(192) k_scan3(
    const float* __restrict__ dts, const float* __restrict__ dtw,
    const float* __restrict__ dtb, const float* __restrict__ xs,
    const float* __restrict__ Bsb, const float* __restrict__ Csb,
    const float* __restrict__ A_logs, const float* __restrict__ Ds,
    const float* __restrict__ SHin, float* __restrict__ out_y) {
  int blk = blockIdx.x;            // bk*C_ + c
  int bk = blk / C_, c = blk % C_;
  int k = bk % K_;
  int d = threadIdx.x;
  float A[NS_];
#pragma unroll
  for (int n = 0; n < NS_; ++n) A[n] = -__expf(A_logs[((size_t)k * DI_ + d) * NS_ + n]);
  float wdt[RK_];
#pragma unroll
  for (int r = 0; r < RK_; ++r) wdt[r] = dtw[((size_t)k * DI_ + d) * RK_ + r];
  float bias = dtb[k * DI_ + d];
  float Dk = Ds[k * DI_ + d];
  float h[NS_];
  size_t hb = (size_t)blk * NS_ * DI_ + d;
#pragma unroll
  for (int n = 0; n < NS_; ++n) h[n] = SHin[hb + (size_t)n * DI_];
  size_t base = (size_t)bk * L_ + (size_t)c * LC_;
  for (int l = 0; l < LC_; ++l) {
    float dl = delta_of(dts + (base + l) * RK_, wdt, bias);
    float u = xs[(base + l) * DI_ + d];
    float du = dl * u;
    const float* Bp = Bsb + (base + l) * NS_;
    const float* Cp = Csb + (base + l) * NS_;
    float yacc = 0.f;
#pragma unroll
    for (int n = 0; n < NS_; ++n) {
      h[n] = __expf(dl * A[n]) * h[n] + du * Bp[n];
      yacc += h[n] * Cp[n];
    }
    out_y[(base + l) * DI_ + d] = yacc + Dk * u;
  }
}

// ---------------------------------------------------------------------------
// K6: merge + LN + gate -> LDS, out-proj GEMM from LDS.  MT=32, grid 432.
// ---------------------------------------------------------------------------
constexpr int MT = 32, GS_ = 196;
__global__ void __launch_bounds__(256) k_head2(
    const float* __restrict__ out_y, const float* __restrict__ zg,
    const float* __restrict__ lnw, const float* __restrict__ lnb,
    const float* __restrict__ wT, float* __restrict__ out) {
  __shared__ float Gs[MT][GS_];
  __shared__ float Ws[32][DM_ + 1];
  int tid = threadIdx.x;
  constexpr int BPS = (B_ * L_) / MT;  // 144
  int m = blockIdx.x / BPS;
  int r0 = (blockIdx.x % BPS) * MT;

  {  // phase 1: 8 threads/row
    int row = tid >> 3, t8 = tid & 7;
    int bl = r0 + row;
    int b = bl / L_, lp = bl % L_;
    int h = lp / W_, w = lp % W_;
    int l0;
    if (m == 0) l0 = lp;
    else if (m == 1) l0 = w * H_ + h;
    else l0 = ((w - h + W_) % W_) * H_ + h;
    size_t basef = ((size_t)b * K_ + m) * L_;
    size_t baser = ((size_t)b * K_ + m + 3) * L_;
    const float* pf = out_y + (basef + l0) * DI_;
    const float* pr = out_y + (baser + (size_t)(L_ - 1 - l0)) * DI_;
    float s = 0.f, s2 = 0.f;
#pragma unroll
    for (int j = 0; j < 6; ++j) {
      int c4 = t8 * 24 + j * 4;
      float4 a = *reinterpret_cast<const float4*>(&pf[c4]);
      float4 bb = *reinterpret_cast<const float4*>(&pr[c4]);
      float4 t;
      t.x = a.x + bb.x; t.y = a.y + bb.y; t.z = a.z + bb.z; t.w = a.w + bb.w;
      s += t.x + t.y + t.z + t.w;
      s2 += t.x * t.x + t.y * t.y + t.z * t.z + t.w * t.w;
      *reinterpret_cast<float4*>(&Gs[row][c4]) = t;
    }
    s += __shfl_xor(s, 1, 64);  s2 += __shfl_xor(s2, 1, 64);
    s += __shfl_xor(s, 2, 64);  s2 += __shfl_xor(s2, 2, 64);
    s += __shfl_xor(s, 4, 64);  s2 += __shfl_xor(s2, 4, 64);
    float mu = s * (1.f / DI_);
    float var = fmaxf(s2 * (1.f / DI_) - mu * mu, 0.f);
    float rs = rsqrtf(var + 1e-5f);
    const float* zp = zg + (size_t)bl * DI_;
#pragma unroll
    for (int j = 0; j < 6; ++j) {
      int c4 = t8 * 24 + j * 4;
      float4 t = *reinterpret_cast<const float4*>(&Gs[row][c4]);
      float4 zv = *reinterpret_cast<const float4*>(&zp[c4]);
      t.x = ((t.x - mu) * rs * lnw[c4 + 0] + lnb[c4 + 0]) * zv.x;
      t.y = ((t.y - mu) * rs * lnw[c4 + 1] + lnb[c4 + 1]) * zv.y;
      t.z = ((t.z - mu) * rs * lnw[c4 + 2] + lnb[c4 + 2]) * zv.z;
      t.w = ((t.w - mu) * rs * lnw[c4 + 3] + lnb[c4 + 3]) * zv.w;
      *reinterpret_cast<float4*>(&Gs[row][c4]) = t;
    }
  }
  __syncthreads();

  int tm = tid >> 4, tn = tid & 15;
  float acc[2][6];
#pragma unroll
  for (int i = 0; i < 2; ++i)
#pragma unroll
    for (int j = 0; j < 6; ++j) acc[i][j] = 0.f;

  for (int k0 = 0; k0 < DI_; k0 += 32) {
#pragma unroll
    for (int it = 0; it < 3; ++it) {
      int i = tid + it * 256;
      int r = i / 24, c4 = (i % 24) << 2;
      const float4 v = *reinterpret_cast<const float4*>(
          &wT[(size_t)(k0 + r) * DM_ + c4]);
      Ws[r][c4] = v.x; Ws[r][c4 + 1] = v.y; Ws[r][c4 + 2] = v.z; Ws[r][c4 + 3] = v.w;
    }
    __syncthreads();
#pragma unroll
    for (int kk = 0; kk < 32; ++kk) {
      float a0 = Gs[tm * 2 + 0][k0 + kk], a1 = Gs[tm * 2 + 1][k0 + kk];
      float w[6];
#pragma unroll
      for (int j = 0; j < 6; ++j) w[j] = Ws[kk][tn * 6 + j];
#pragma unroll
      for (int j = 0; j < 6; ++j) {
        acc[0][j] += a0 * w[j];
        acc[1][j] += a1 * w[j];
      }
    }
    __syncthreads();
  }
  size_t obase = ((size_t)m * (B_ * L_) + r0) * DM_;
#pragma unroll
  for (int i = 0; i < 2; ++i) {
    size_t ob = obase + (size_t)(tm * 2 + i) * DM_ + tn * 6;
#pragma unroll
    for (int j = 0; j < 6; ++j) out[ob + j] = acc[i][j];
  }
}

}  // namespace

extern "C" void kernel_launch(void* const* d_in, const int* in_sizes, int n_in,
                              void* d_out, int out_size, void* d_ws, size_t ws_size,
                              hipStream_t stream) {
  const float* x = (const float*)d_in[0];
  const float* y = (const float*)d_in[1];
  const float* kin = (const float*)d_in[2];
  const float* in_proj_w = (const float*)d_in[3];
  const float* conv_w = (const float*)d_in[4];
  const float* conv_b = (const float*)d_in[5];
  const float* x_proj_w = (const float*)d_in[6];
  const float* dt_w = (const float*)d_in[7];
  const float* dt_b = (const float*)d_in[8];
  const float* A_logs = (const float*)d_in[9];
  const float* Ds = (const float*)d_in[10];
  const float* ln_w = (const float*)d_in[11];
  const float* ln_b = (const float*)d_in[12];
  const float* out_proj_w = (const float*)d_in[13];
  float* out = (float*)d_out;

  float* ws = (float*)d_ws;
  const size_t BLD = (size_t)B_ * L_ * DI_;                 // 884736
  const size_t BKLD = (size_t)B_ * K_ * L_ * DI_;           // 5308416
  const size_t BKLN = (size_t)B_ * K_ * L_ * NS_;           // 442368
  const size_t PSN = (size_t)B_ * K_ * C_ * NS_ * DI_;
  float* xv = ws;             ws += BLD;
  float* yv = ws;             ws += BLD;
  float* zg = ws;             ws += BLD;
  float* xs = ws;             ws += BKLD;
  float* Bsb = ws;            ws += BKLN;
  float* Csb = ws;            ws += BKLN;
  float* out_y = ws;          ws += BKLD;
  float* SHin = ws;           ws += PSN;
  float* Sdl = ws;            ws += (size_t)B_ * K_ * C_ * DI_;
  float* wT = ws;             ws += (size_t)DI_ * DM_;
  float* xpwT = ws;           ws += (size_t)K_ * DI_ * NPAD;
  float* wInT = ws;           ws += (size_t)DM_ * 2 * DI_;
  float* dts = ws;            ws += (size_t)B_ * K_ * L_ * RK_;
  float* cwT = ws;            ws += (size_t)9 * DI_;

  k_prep<<<DM_ + K_ + DI_ + 1, 384, 0, stream>>>(in_proj_w, x_proj_w, out_proj_w,
                                                 conv_w, wInT, xpwT, wT, cwT);
  k_inproj2<<<3 * B_ * L_ / IM, 256, 0, stream>>>(x, y, kin, wInT, xv, yv, zg);
  k_conv_xs<<<B_ * L_ / 4, 192, 0, stream>>>(xv, yv, cwT, conv_b, xs);
  k_xdbl3<<<B_ * K_ * L_ / XM, 256, 0, stream>>>(xs, xpwT, dts, Bsb, Csb);
  k_scan1<<<B_ * K_ * C_, 192, 0, stream>>>(dts, dt_w, dt_b, xs, Bsb, A_logs, Sdl, SHin);
  k_scan2<<<B_ * K_ * NS_, 192, 0, stream>>>(Sdl, A_logs, SHin);
  k_scan3<<<B_ * K_ * C_, 192, 0, stream>>>(dts, dt_w, dt_b, xs, Bsb, Csb, A_logs,
                                            Ds, SHin, out_y);
  k_head2<<<3 * B_ * L_ / MT, 256, 0, stream>>>(out_y, zg, ln_w, ln_b, wT, out);
}